// Round 2
// baseline (10531.410 us; speedup 1.0000x reference)
//
#include <hip/hip_runtime.h>

#define T_ 8192
#define B_ 4
#define F_ 256

// ============================================================================
// init: xi5[b,t,n] = sum_i x[b,i,t,n]*cw[4,i] + cb[4]   (channel S only)
// ============================================================================
__global__ __launch_bounds__(256) void init_k(
    const float* __restrict__ x, const float* __restrict__ cw,
    const float* __restrict__ cb, float* __restrict__ xi5)
{
  size_t idx = (size_t)blockIdx.x * 256 + threadIdx.x;   // over B*T*64
  int n = (int)(idx & 63);
  int t = (int)((idx >> 6) & (T_ - 1));
  int b = (int)(idx >> 19);
  float x0 = x[(((size_t)b*3 + 0)*T_ + t)*64 + n];
  float x1 = x[(((size_t)b*3 + 1)*T_ + t)*64 + n];
  float x2 = x[(((size_t)b*3 + 2)*T_ + t)*64 + n];
  xi5[idx] = cb[4] + x0*cw[12] + x1*cw[13] + x2*cw[14];
}

// fs channel c (0..3) of the input projection, recomputed per SFI layer
__global__ __launch_bounds__(256) void fs_k(
    const float* __restrict__ x, const float* __restrict__ cw,
    const float* __restrict__ cb, float* __restrict__ fs, int c)
{
  size_t idx = (size_t)blockIdx.x * 256 + threadIdx.x;   // over B*T*64
  int n = (int)(idx & 63);
  int t = (int)((idx >> 6) & (T_ - 1));
  int b = (int)(idx >> 19);
  float x0 = x[(((size_t)b*3 + 0)*T_ + t)*64 + n];
  float x1 = x[(((size_t)b*3 + 1)*T_ + t)*64 + n];
  float x2 = x[(((size_t)b*3 + 2)*T_ + t)*64 + n];
  fs[idx] = cb[c] + x0*cw[c*3] + x1*cw[c*3+1] + x2*cw[c*3+2];
}

// ============================================================================
// Generic row-GEMM: C[b,t,n] = act( sum_k a[b,t,k]*W[n,k] (+bias[n]) ) (+resid)
// A: (B,T,K)  W: (N,K) row-major, optionally per-batch (wbs = batch stride)
// NORM: a = (A - mean[k]) * iv[k] with per-batch stats2[b][k]=mean,[256+k]=iv
// tile 128x128, block 256, 8x8 per thread, K-tile 16.
// ACT: 0=none 1=relu 2=sigmoid 3=gelu(exact)
// ============================================================================
template<int ACT, int NORM>
__global__ __launch_bounds__(256) void gemm_k(
    const float* __restrict__ A, const float* __restrict__ W,
    const float* __restrict__ bias, const float* __restrict__ resid,
    float* __restrict__ C, int K, int N, size_t wbs,
    const float* __restrict__ stats2)
{
  int b  = blockIdx.z;
  int t0 = blockIdx.x * 128;
  int n0 = blockIdx.y * 128;
  const float* Ab = A + (size_t)b*T_*K;
  const float* Wb = W + (size_t)b*wbs;
  const float* st = NORM ? (stats2 + b*512) : nullptr;
  __shared__ float As[16][132];
  __shared__ float Ws[16][132];
  int tid = threadIdx.x;
  int tx = tid & 15, ty = tid >> 4;
  int r  = tid >> 1;
  int c8 = (tid & 1) * 8;
  float acc[8][8] = {};
  for (int k0 = 0; k0 < K; k0 += 16) {
    float av[8], wv[8];
    *(float4*)(av)   = *(const float4*)(Ab + (size_t)(t0 + r)*K + k0 + c8);
    *(float4*)(av+4) = *(const float4*)(Ab + (size_t)(t0 + r)*K + k0 + c8 + 4);
    *(float4*)(wv)   = *(const float4*)(Wb + (size_t)(n0 + r)*K + k0 + c8);
    *(float4*)(wv+4) = *(const float4*)(Wb + (size_t)(n0 + r)*K + k0 + c8 + 4);
    if (NORM) {
      #pragma unroll
      for (int u = 0; u < 8; ++u)
        av[u] = (av[u] - st[k0 + c8 + u]) * st[256 + k0 + c8 + u];
    }
    #pragma unroll
    for (int u = 0; u < 8; ++u) { As[c8+u][r] = av[u]; Ws[c8+u][r] = wv[u]; }
    __syncthreads();
    #pragma unroll
    for (int kk = 0; kk < 16; ++kk) {
      float a[8], w[8];
      #pragma unroll
      for (int i = 0; i < 8; ++i) a[i] = As[kk][ty*8 + i];
      #pragma unroll
      for (int j = 0; j < 8; ++j) w[j] = Ws[kk][tx*8 + j];
      #pragma unroll
      for (int i = 0; i < 8; ++i)
        #pragma unroll
        for (int j = 0; j < 8; ++j)
          acc[i][j] = fmaf(a[i], w[j], acc[i][j]);
    }
    __syncthreads();
  }
  #pragma unroll
  for (int i = 0; i < 8; ++i) {
    int t = t0 + ty*8 + i;
    size_t rowoff = ((size_t)b*T_ + t)*(size_t)N;
    #pragma unroll
    for (int j = 0; j < 8; ++j) {
      int n = n0 + tx*8 + j;
      float v = acc[i][j];
      if (bias) v += bias[n];
      if (ACT == 1) v = fmaxf(v, 0.f);
      if (ACT == 2) v = 1.f/(1.f + expf(-v));
      if (ACT == 3) v = 0.5f*v*(1.f + erff(v*0.7071067811865475f));
      if (resid) v += resid[rowoff + n];
      C[rowoff + n] = v;
    }
  }
}

// ============================================================================
// Dilated conv (taps -1,0,+1 * dil), K=N=256, zero pad along T, + bias, relu.
// W layout: (out=256, in=256, 3)
// ============================================================================
__global__ __launch_bounds__(256) void conv_k(
    const float* __restrict__ X, const float* __restrict__ Wc,
    const float* __restrict__ bias, float* __restrict__ C, int dil)
{
  int b  = blockIdx.z;
  int t0 = blockIdx.x * 128;
  int n0 = blockIdx.y * 128;
  const float* Xb = X + (size_t)b*T_*256;
  __shared__ float As[16][132];
  __shared__ float Ws[16][132];
  int tid = threadIdx.x;
  int tx = tid & 15, ty = tid >> 4;
  int r  = tid >> 1;
  int c8 = (tid & 1) * 8;
  float acc[8][8] = {};
  for (int tap = 0; tap < 3; ++tap) {
    int off = (tap - 1) * dil;
    for (int k0 = 0; k0 < 256; k0 += 16) {
      int rt = t0 + r + off;
      bool ok = ((unsigned)rt < (unsigned)T_);
      float4 a0 = make_float4(0,0,0,0), a1 = make_float4(0,0,0,0);
      if (ok) {
        a0 = *(const float4*)(Xb + (size_t)rt*256 + k0 + c8);
        a1 = *(const float4*)(Xb + (size_t)rt*256 + k0 + c8 + 4);
      }
      As[c8+0][r]=a0.x; As[c8+1][r]=a0.y; As[c8+2][r]=a0.z; As[c8+3][r]=a0.w;
      As[c8+4][r]=a1.x; As[c8+5][r]=a1.y; As[c8+6][r]=a1.z; As[c8+7][r]=a1.w;
      const float* wsrc = Wc + (size_t)(n0 + r)*768 + (size_t)(k0 + c8)*3 + tap;
      #pragma unroll
      for (int u = 0; u < 8; ++u) Ws[c8+u][r] = wsrc[u*3];
      __syncthreads();
      #pragma unroll
      for (int kk = 0; kk < 16; ++kk) {
        float a[8], w[8];
        #pragma unroll
        for (int i = 0; i < 8; ++i) a[i] = As[kk][ty*8 + i];
        #pragma unroll
        for (int j = 0; j < 8; ++j) w[j] = Ws[kk][tx*8 + j];
        #pragma unroll
        for (int i = 0; i < 8; ++i)
          #pragma unroll
          for (int j = 0; j < 8; ++j)
            acc[i][j] = fmaf(a[i], w[j], acc[i][j]);
      }
      __syncthreads();
    }
  }
  #pragma unroll
  for (int i = 0; i < 8; ++i) {
    int t = t0 + ty*8 + i;
    size_t rowoff = ((size_t)b*T_ + t)*256;
    #pragma unroll
    for (int j = 0; j < 8; ++j) {
      int n = n0 + tx*8 + j;
      C[rowoff + n] = fmaxf(acc[i][j] + bias[n], 0.f);
    }
  }
}

// ============================================================================
// Instance-norm stats: per (b,f) sum / sumsq over T (atomic partials),
// then finalized in-place to mean / inv-std.
// ============================================================================
__global__ __launch_bounds__(256) void stats_k(
    const float* __restrict__ Xo, float* __restrict__ stats)
{
  int b  = blockIdx.y;
  int t0 = blockIdx.x * (T_/32);
  int f  = threadIdx.x;
  float s = 0.f, s2 = 0.f;
  for (int t = t0; t < t0 + T_/32; ++t) {
    float v = Xo[((size_t)b*T_ + t)*256 + f];
    s += v; s2 += v*v;
  }
  atomicAdd(&stats[b*512 + f], s);
  atomicAdd(&stats[b*512 + 256 + f], s2);
}

__global__ __launch_bounds__(256) void finstats_k(float* __restrict__ stats)
{
  int i = blockIdx.x * 256 + threadIdx.x;   // B*256
  int b = i >> 8, f = i & 255;
  float s  = stats[b*512 + f];
  float s2 = stats[b*512 + 256 + f];
  float m  = s * (1.f/T_);
  float v  = s2 * (1.f/T_) - m*m;
  stats[b*512 + f]       = m;
  stats[b*512 + 256 + f] = rsqrtf(fmaxf(v, 0.f) + 1e-5f);
}

// ============================================================================
// Linear attention: KV[d,e] = sum_t K[t,d]*V[t,e]; Ksum[d] = sum_t K[t,d]
// kv buffer per (b,h): 64*64 KV + 64 Ksum = 4160 floats
// ============================================================================
__global__ __launch_bounds__(256) void kv_reduce_k(
    const float* __restrict__ Kb, const float* __restrict__ Vb,
    float* __restrict__ kv)
{
  int bh = blockIdx.y; int b = bh >> 2; int h = bh & 3;
  int t0 = blockIdx.x * (T_/32);           // 256 t's per block
  __shared__ float Ks[64][65];
  __shared__ float Vs[64][65];
  int tid = threadIdx.x;
  int d  = tid >> 2;
  int e0 = (tid & 3) * 16;
  float acc[16] = {};
  float ksum = 0.f;
  int rr = tid >> 4;          // 0..15
  int c4 = (tid & 15) * 4;    // 0..60
  for (int c = 0; c < 4; ++c) {
    int tb = t0 + c*64;
    #pragma unroll
    for (int q = 0; q < 4; ++q) {
      int row = rr + q*16;
      const float* ks = Kb + ((size_t)b*T_ + tb + row)*256 + h*64 + c4;
      const float* vs = Vb + ((size_t)b*T_ + tb + row)*256 + h*64 + c4;
      float4 kvv = *(const float4*)ks;
      float4 vvv = *(const float4*)vs;
      Ks[row][c4]=kvv.x; Ks[row][c4+1]=kvv.y; Ks[row][c4+2]=kvv.z; Ks[row][c4+3]=kvv.w;
      Vs[row][c4]=vvv.x; Vs[row][c4+1]=vvv.y; Vs[row][c4+2]=vvv.z; Vs[row][c4+3]=vvv.w;
    }
    __syncthreads();
    #pragma unroll
    for (int tt = 0; tt < 64; ++tt) {
      float kd = Ks[tt][d];
      if (e0 == 0) ksum += kd;
      #pragma unroll
      for (int j = 0; j < 16; ++j) acc[j] = fmaf(kd, Vs[tt][e0+j], acc[j]);
    }
    __syncthreads();
  }
  float* dst = kv + (size_t)bh*4160;
  #pragma unroll
  for (int j = 0; j < 16; ++j) atomicAdd(&dst[d*64 + e0 + j], acc[j]);
  if (e0 == 0) atomicAdd(&dst[4096 + d], ksum);
}

// o[t,e] = (sum_d Q[t,d]*KV[d,e]) / (sum_d Q[t,d]*(Ksum[d]+1e-6))
// O may alias Qb: the block consumes its whole Q tile into LDS before writing.
__global__ __launch_bounds__(256) void att_apply_k(
    const float* __restrict__ Qb, const float* __restrict__ kv,
    float* __restrict__ O)
{
  int bh = blockIdx.y; int b = bh >> 2; int h = bh & 3;
  int t0 = blockIdx.x * 64;
  __shared__ float KVs[64][65];
  __shared__ float Qs[64][65];
  __shared__ float ks[64];
  int tid = threadIdx.x;
  const float* src = kv + (size_t)bh*4160;
  #pragma unroll
  for (int i = 0; i < 16; ++i) {
    int idx = tid + i*256;
    KVs[idx >> 6][idx & 63] = src[idx];
  }
  if (tid < 64) ks[tid] = src[4096 + tid] + 1e-6f;
  {
    int r = tid >> 2, c0 = (tid & 3) * 16;
    #pragma unroll
    for (int j = 0; j < 16; j += 4) {
      float4 q = *(const float4*)(Qb + ((size_t)b*T_ + t0 + r)*256 + h*64 + c0 + j);
      Qs[r][c0+j]=q.x; Qs[r][c0+j+1]=q.y; Qs[r][c0+j+2]=q.z; Qs[r][c0+j+3]=q.w;
    }
  }
  __syncthreads();
  int t = tid >> 2, e0 = (tid & 3) * 16;
  float acc[16] = {};
  float den = 0.f;
  #pragma unroll 4
  for (int dd = 0; dd < 64; ++dd) {
    float qv = Qs[t][dd];
    den = fmaf(qv, ks[dd], den);
    #pragma unroll
    for (int j = 0; j < 16; ++j) acc[j] = fmaf(qv, KVs[dd][e0+j], acc[j]);
  }
  float z = 1.f / den;
  float* dst = O + ((size_t)b*T_ + t0 + t)*256 + h*64 + e0;
  #pragma unroll
  for (int j = 0; j < 16; ++j) dst[j] = acc[j] * z;
}

// ============================================================================
// SFI gram: G[b,c,d] += sum over t-chunk of A[b,t,c]*B[b,t,d]
// ============================================================================
__global__ __launch_bounds__(256) void gram_k(
    const float* __restrict__ Ab, const float* __restrict__ Bb,
    float* __restrict__ G)
{
  int b  = blockIdx.z;
  int c0 = (blockIdx.y >> 1) * 128;
  int d0 = (blockIdx.y & 1) * 128;
  int t0 = blockIdx.x * (T_/16);   // 512 t's
  __shared__ float As[8][132];
  __shared__ float Bs[8][132];
  int tid = threadIdx.x, tx = tid & 15, ty = tid >> 4;
  int kk = tid >> 5;          // 0..7
  int cc = (tid & 31) * 4;    // 0..124
  float acc[8][8] = {};
  for (int k0 = 0; k0 < 512; k0 += 8) {
    size_t row = ((size_t)b*T_ + t0 + k0 + kk) * 256;
    float4 av = *(const float4*)(Ab + row + c0 + cc);
    float4 bv = *(const float4*)(Bb + row + d0 + cc);
    As[kk][cc]=av.x; As[kk][cc+1]=av.y; As[kk][cc+2]=av.z; As[kk][cc+3]=av.w;
    Bs[kk][cc]=bv.x; Bs[kk][cc+1]=bv.y; Bs[kk][cc+2]=bv.z; Bs[kk][cc+3]=bv.w;
    __syncthreads();
    #pragma unroll
    for (int q = 0; q < 8; ++q) {
      float a[8], w[8];
      #pragma unroll
      for (int i = 0; i < 8; ++i) a[i] = As[q][ty*8 + i];
      #pragma unroll
      for (int j = 0; j < 8; ++j) w[j] = Bs[q][tx*8 + j];
      #pragma unroll
      for (int i = 0; i < 8; ++i)
        #pragma unroll
        for (int j = 0; j < 8; ++j)
          acc[i][j] = fmaf(a[i], w[j], acc[i][j]);
    }
    __syncthreads();
  }
  #pragma unroll
  for (int i = 0; i < 8; ++i)
    #pragma unroll
    for (int j = 0; j < 8; ++j)
      atomicAdd(&G[((size_t)b << 16) + (size_t)(c0 + ty*8 + i)*256 + d0 + tx*8 + j],
                acc[i][j]);
}

// softmax over rows of G (1024 rows of 256), with pre-scale 1/T
__global__ __launch_bounds__(64) void softmax_k(float* __restrict__ G)
{
  int row = blockIdx.x;
  float* p = G + (size_t)row * 256;
  int l = threadIdx.x;
  float v[4];
  float mx = -1e30f;
  #pragma unroll
  for (int j = 0; j < 4; ++j) { v[j] = p[l*4 + j] * (1.f/T_); mx = fmaxf(mx, v[j]); }
  #pragma unroll
  for (int off = 32; off > 0; off >>= 1) mx = fmaxf(mx, __shfl_xor(mx, off));
  float s = 0.f;
  #pragma unroll
  for (int j = 0; j < 4; ++j) { v[j] = expf(v[j] - mx); s += v[j]; }
  #pragma unroll
  for (int off = 32; off > 0; off >>= 1) s += __shfl_xor(s, off);
  float inv = 1.f / s;
  #pragma unroll
  for (int j = 0; j < 4; ++j) p[l*4 + j] = v[j] * inv;
}

// ============================================================================
// Final: out[b,o,t] = (sum_c fst[b,t,c]*Wn[o,c] + bn[o]) * mask[b,t]
// 32 t-rows per block -> 32*257*4 = 32.9 KB LDS (64-row version overflowed 64KB)
// ============================================================================
__global__ __launch_bounds__(256) void final_k(
    const float* __restrict__ A, const float* __restrict__ Wn,
    const float* __restrict__ bn, const float* __restrict__ mask,
    float* __restrict__ out)
{
  int b = blockIdx.y, t0 = blockIdx.x * 32;
  __shared__ float As[32][257];
  int tid = threadIdx.x;
  #pragma unroll
  for (int i = 0; i < 8; ++i) {
    int f4 = tid + i*256;            // 0..2047
    int rr = f4 >> 6;
    int c4 = (f4 & 63) * 4;
    float4 v = *(const float4*)(A + ((size_t)b*T_ + t0 + rr)*256 + c4);
    As[rr][c4]=v.x; As[rr][c4+1]=v.y; As[rr][c4+2]=v.z; As[rr][c4+3]=v.w;
  }
  __syncthreads();
  int t  = tid & 31;
  int og = tid >> 5;                 // 8 groups x 6 outputs
  float m = mask[(size_t)b*T_ + t0 + t];
  for (int o = og*6; o < og*6 + 6; ++o) {
    float acc = bn[o];
    const float* wr = Wn + o*256;
    #pragma unroll 8
    for (int c = 0; c < 256; ++c) acc = fmaf(As[t][c], wr[c], acc);
    out[((size_t)b*48 + o)*T_ + t0 + t] = acc * m;
  }
}

// ============================================================================
extern "C" void kernel_launch(void* const* d_in, const int* in_sizes, int n_in,
                              void* d_out, int out_size, void* d_ws, size_t ws_size,
                              hipStream_t stream) {
  const float* x         = (const float*)d_in[0];
  const float* mask      = (const float*)d_in[1];
  const float* conv_in_w = (const float*)d_in[2];
  const float* conv_in_b = (const float*)d_in[3];
  const float* conv_t_w  = (const float*)d_in[4];
  const float* conv_t_b  = (const float*)d_in[5];
  const float* sfi_cs_w  = (const float*)d_in[6];
  const float* sfi_cs_b  = (const float*)d_in[7];
  const float* sfi_ff1_w = (const float*)d_in[8];
  const float* sfi_ff1_b = (const float*)d_in[9];
  const float* sfi_ff2_w = (const float*)d_in[10];
  const float* sfi_ff2_b = (const float*)d_in[11];
  const float* ff_w      = (const float*)d_in[12];
  const float* ff_b      = (const float*)d_in[13];
  const float* qw = (const float*)d_in[14]; const float* qb = (const float*)d_in[15];
  const float* kw = (const float*)d_in[16]; const float* kb = (const float*)d_in[17];
  const float* vw = (const float*)d_in[18]; const float* vb = (const float*)d_in[19];
  const float* ow = (const float*)d_in[20]; const float* ob = (const float*)d_in[21];
  const float* co_w = (const float*)d_in[22]; const float* co_b = (const float*)d_in[23];
  const float* out_w = (const float*)d_in[24]; const float* out_b = (const float*)d_in[25];

  float* ws = (float*)d_ws;
  const size_t BT = (size_t)B_ * T_;
  // ---- workspace layout (floats) ----  total ~44.4M floats = 178 MB
  float* small = ws;                        // BT*64   (xi5, then per-SFI fs)
  float* fstA  = small + BT*64;             // BT*256
  float* fstB  = fstA + BT*256;
  float* Tb1   = fstB + BT*256;
  float* Tb2   = Tb1 + BT*256;
  float* Tb3   = Tb2 + BT*256;
  float* gram  = Tb3 + BT*256;              // B*256*256
  float* stats = gram + (size_t)B_*256*256; // B*512
  float* kvbuf = stats + B_*512;            // 16*4160

  dim3 g128(T_/128, 2, B_);
  dim3 b256(256);

  init_k<<<dim3((unsigned)(BT*64/256)), b256, 0, stream>>>(x, conv_in_w, conv_in_b, small);
  gemm_k<0,0><<<g128, b256, 0, stream>>>(small, conv_t_w, conv_t_b, nullptr, fstA,
                                         64, 256, 0, nullptr);

  float* fst  = fstA;
  float* fstN = fstB;
  int count = 0;
  for (int i = 0; i < 10; ++i) {
    if (i == 1 || i == 3 || i == 5 || i == 7) {
      // ---- SFI ----
      fs_k<<<dim3((unsigned)(BT*64/256)), b256, 0, stream>>>(x, conv_in_w, conv_in_b, small, count);
      gemm_k<0,0><<<g128, b256, 0, stream>>>(small, sfi_cs_w + (size_t)count*256*64,
                                             sfi_cs_b + count*256, nullptr, Tb1,
                                             64, 256, 0, nullptr);
      hipMemsetAsync(gram, 0, (size_t)B_*256*256*sizeof(float), stream);
      gram_k<<<dim3(16, 4, B_), b256, 0, stream>>>(Tb1, fst, gram);
      softmax_k<<<dim3(B_*256), dim3(64), 0, stream>>>(gram);
      gemm_k<0,0><<<g128, b256, 0, stream>>>(fst, gram, nullptr, fst, Tb2,
                                             256, 256, (size_t)256*256, nullptr);
      gemm_k<3,0><<<g128, b256, 0, stream>>>(Tb2, sfi_ff1_w + (size_t)count*256*256,
                                             sfi_ff1_b + count*256, nullptr, Tb3,
                                             256, 256, 0, nullptr);
      gemm_k<0,0><<<g128, b256, 0, stream>>>(Tb3, sfi_ff2_w + (size_t)count*256*256,
                                             sfi_ff2_b + count*256, fst, fstN,
                                             256, 256, 0, nullptr);
      float* tmp = fst; fst = fstN; fstN = tmp;
      ++count;
    }
    // ---- attention module ----
    int dil = 1 << i;
    // conv_out -> fstN (scratch until co-gemm overwrites it)
    conv_k<<<g128, b256, 0, stream>>>(fst, ff_w + (size_t)i*256*256*3, ff_b + i*256, fstN, dil);
    hipMemsetAsync(stats, 0, (size_t)B_*512*sizeof(float), stream);
    stats_k<<<dim3(32, B_), b256, 0, stream>>>(fstN, stats);
    finstats_k<<<dim3(B_), b256, 0, stream>>>(stats);
    // Q/K/V with fused instance-norm on the A operand
    gemm_k<2,1><<<g128, b256, 0, stream>>>(fstN, qw + (size_t)i*256*256, qb + i*256,
                                           nullptr, Tb1, 256, 256, 0, stats);
    gemm_k<2,1><<<g128, b256, 0, stream>>>(fstN, kw + (size_t)i*256*256, kb + i*256,
                                           nullptr, Tb2, 256, 256, 0, stats);
    gemm_k<0,1><<<g128, b256, 0, stream>>>(fstN, vw + (size_t)i*256*256, vb + i*256,
                                           nullptr, Tb3, 256, 256, 0, stats);
    hipMemsetAsync(kvbuf, 0, (size_t)16*4160*sizeof(float), stream);
    kv_reduce_k<<<dim3(32, 16), b256, 0, stream>>>(Tb2, Tb3, kvbuf);
    att_apply_k<<<dim3(T_/64, 16), b256, 0, stream>>>(Tb1, kvbuf, Tb1);   // in-place
    // o-proj + conv_out residual
    gemm_k<0,0><<<g128, b256, 0, stream>>>(Tb1, ow + (size_t)i*256*256, ob + i*256,
                                           fstN, Tb2, 256, 256, 0, nullptr);
    // co-proj + fst residual -> new fst
    gemm_k<0,0><<<g128, b256, 0, stream>>>(Tb2, co_w + (size_t)i*256*256, co_b + i*256,
                                           fst, fstN, 256, 256, 0, nullptr);
    float* tmp = fst; fst = fstN; fstN = tmp;
  }
  final_k<<<dim3(T_/32, B_), b256, 0, stream>>>(fst, out_w, out_b, mask, (float*)d_out);
}

// Round 3
// 7500.556 us; speedup vs baseline: 1.4041x; 1.4041x over previous
//
#include <hip/hip_runtime.h>

#define T_ 8192
#define B_ 4
#define F_ 256

typedef _Float16 half4 __attribute__((ext_vector_type(4)));
typedef _Float16 half8 __attribute__((ext_vector_type(8)));
typedef float    f32x4 __attribute__((ext_vector_type(4)));

// ============================================================================
// init: xi5[b,t,n] = sum_i x[b,i,t,n]*cw[4,i] + cb[4]   (channel S only)
// ============================================================================
__global__ __launch_bounds__(256) void init_k(
    const float* __restrict__ x, const float* __restrict__ cw,
    const float* __restrict__ cb, float* __restrict__ xi5)
{
  size_t idx = (size_t)blockIdx.x * 256 + threadIdx.x;   // over B*T*64
  int n = (int)(idx & 63);
  int t = (int)((idx >> 6) & (T_ - 1));
  int b = (int)(idx >> 19);
  float x0 = x[(((size_t)b*3 + 0)*T_ + t)*64 + n];
  float x1 = x[(((size_t)b*3 + 1)*T_ + t)*64 + n];
  float x2 = x[(((size_t)b*3 + 2)*T_ + t)*64 + n];
  xi5[idx] = cb[4] + x0*cw[12] + x1*cw[13] + x2*cw[14];
}

// fs channel c (0..3) of the input projection, recomputed per SFI layer
__global__ __launch_bounds__(256) void fs_k(
    const float* __restrict__ x, const float* __restrict__ cw,
    const float* __restrict__ cb, float* __restrict__ fs, int c)
{
  size_t idx = (size_t)blockIdx.x * 256 + threadIdx.x;   // over B*T*64
  int n = (int)(idx & 63);
  int t = (int)((idx >> 6) & (T_ - 1));
  int b = (int)(idx >> 19);
  float x0 = x[(((size_t)b*3 + 0)*T_ + t)*64 + n];
  float x1 = x[(((size_t)b*3 + 1)*T_ + t)*64 + n];
  float x2 = x[(((size_t)b*3 + 2)*T_ + t)*64 + n];
  fs[idx] = cb[c] + x0*cw[c*3] + x1*cw[c*3+1] + x2*cw[c*3+2];
}

// conv weight transpose: src[n][k][tap] (f32) -> dst[tap][n][k] (f32)
__global__ __launch_bounds__(256) void convw_prep_k(
    const float* __restrict__ src, float* __restrict__ dst)
{
  int idx = blockIdx.x*256 + threadIdx.x;   // 3*256*256
  int k = idx & 255, n = (idx >> 8) & 255, tap = idx >> 16;
  dst[idx] = src[(((size_t)n << 8) + k)*3 + tap];
  (void)tap;
}

// ============================================================================
// fp16x2 split-precision MFMA GEMM.
// C[b,t,n] = act( sum_k a[b,t,k]*W[n,k] (+bias[n]) ) (+resid), N = 256 fixed.
// A: (B,T,K) f32; W: (N,K) f32 (per-batch if wbs!=0).
// D = Ah*Wh + Al*Wh + Ah*Wl  (Al*Wl term ~2^-22 relative, dropped) -> f32-level
// accuracy at MFMA speed.  Tile 128x128, 4 waves (2x2), 16x16x32 MFMA.
// NORM: a = (A-mean[k])*iv[k], stats2[b][k]=mean, [256+k]=iv.
// ACT: 0=none 1=relu 2=sigmoid 3=gelu(exact)
// ============================================================================
template<int ACT, int NORM>
__global__ __launch_bounds__(256, 2) void gemm_h(
    const float* __restrict__ A, const float* __restrict__ W,
    const float* __restrict__ bias, const float* __restrict__ resid,
    float* __restrict__ C, int K, size_t wbs,
    const float* __restrict__ stats2)
{
  int b  = blockIdx.z;
  int n0 = blockIdx.x * 128;      // x = n so A-sharing blocks are adjacent
  int t0 = blockIdx.y * 128;
  const float* Ab = A + (size_t)b*T_*K;
  const float* Wb = W + (size_t)b*wbs;
  const float* st = NORM ? (stats2 + b*512) : nullptr;
  __shared__ _Float16 Ah[128][40], Al[128][40], Wh[128][40], Wl[128][40];
  int tid = threadIdx.x, l = tid & 63, wid = tid >> 6;
  int wr = wid >> 1, wc = wid & 1, lr = l & 15, kg = l >> 4;
  f32x4 acc[4][4];
  #pragma unroll
  for (int m = 0; m < 4; ++m)
    #pragma unroll
    for (int n = 0; n < 4; ++n) acc[m][n] = (f32x4){0.f,0.f,0.f,0.f};

  for (int k0 = 0; k0 < K; k0 += 32) {
    #pragma unroll
    for (int i = 0; i < 4; ++i) {
      int q = tid + i*256;                 // 0..1023
      int row = q >> 3, kq = (q & 7) * 4;
      float4 av = *(const float4*)(Ab + (size_t)(t0 + row)*K + k0 + kq);
      if (NORM) {
        av.x = (av.x - st[k0+kq+0]) * st[256+k0+kq+0];
        av.y = (av.y - st[k0+kq+1]) * st[256+k0+kq+1];
        av.z = (av.z - st[k0+kq+2]) * st[256+k0+kq+2];
        av.w = (av.w - st[k0+kq+3]) * st[256+k0+kq+3];
      }
      float4 wv = *(const float4*)(Wb + (size_t)(n0 + row)*K + k0 + kq);
      half4 hh, ll;
      hh[0]=(_Float16)av.x; ll[0]=(_Float16)(av.x-(float)hh[0]);
      hh[1]=(_Float16)av.y; ll[1]=(_Float16)(av.y-(float)hh[1]);
      hh[2]=(_Float16)av.z; ll[2]=(_Float16)(av.z-(float)hh[2]);
      hh[3]=(_Float16)av.w; ll[3]=(_Float16)(av.w-(float)hh[3]);
      *(half4*)&Ah[row][kq] = hh; *(half4*)&Al[row][kq] = ll;
      hh[0]=(_Float16)wv.x; ll[0]=(_Float16)(wv.x-(float)hh[0]);
      hh[1]=(_Float16)wv.y; ll[1]=(_Float16)(wv.y-(float)hh[1]);
      hh[2]=(_Float16)wv.z; ll[2]=(_Float16)(wv.z-(float)hh[2]);
      hh[3]=(_Float16)wv.w; ll[3]=(_Float16)(wv.w-(float)hh[3]);
      *(half4*)&Wh[row][kq] = hh; *(half4*)&Wl[row][kq] = ll;
    }
    __syncthreads();
    half8 ah[4], al[4], wh[4], wl[4];
    #pragma unroll
    for (int m = 0; m < 4; ++m) {
      ah[m] = *(const half8*)&Ah[wr*64 + m*16 + lr][kg*8];
      al[m] = *(const half8*)&Al[wr*64 + m*16 + lr][kg*8];
    }
    #pragma unroll
    for (int n = 0; n < 4; ++n) {
      wh[n] = *(const half8*)&Wh[wc*64 + n*16 + lr][kg*8];
      wl[n] = *(const half8*)&Wl[wc*64 + n*16 + lr][kg*8];
    }
    #pragma unroll
    for (int m = 0; m < 4; ++m)
      #pragma unroll
      for (int n = 0; n < 4; ++n) {
        acc[m][n] = __builtin_amdgcn_mfma_f32_16x16x32_f16(ah[m], wh[n], acc[m][n], 0, 0, 0);
        acc[m][n] = __builtin_amdgcn_mfma_f32_16x16x32_f16(al[m], wh[n], acc[m][n], 0, 0, 0);
        acc[m][n] = __builtin_amdgcn_mfma_f32_16x16x32_f16(ah[m], wl[n], acc[m][n], 0, 0, 0);
      }
    __syncthreads();
  }
  // epilogue: D row=(l>>4)*4+r, col=l&15 within each 16x16 tile
  #pragma unroll
  for (int m = 0; m < 4; ++m)
    #pragma unroll
    for (int n = 0; n < 4; ++n) {
      int col = n0 + wc*64 + n*16 + lr;
      float bi = bias ? bias[col] : 0.f;
      #pragma unroll
      for (int r = 0; r < 4; ++r) {
        int row = t0 + wr*64 + m*16 + kg*4 + r;
        size_t off = ((size_t)b*T_ + row)*256 + col;
        float v = acc[m][n][r] + bi;
        if (ACT == 1) v = fmaxf(v, 0.f);
        if (ACT == 2) v = 1.f/(1.f + expf(-v));
        if (ACT == 3) v = 0.5f*v*(1.f + erff(v*0.7071067811865475f));
        if (resid) v += resid[off];
        C[off] = v;
      }
    }
}

// ============================================================================
// Dilated conv as 3-tap accumulated fp16x2 MFMA GEMM. Wt: [tap][n][k] f32.
// ============================================================================
__global__ __launch_bounds__(256, 2) void conv_h(
    const float* __restrict__ X, const float* __restrict__ Wt,
    const float* __restrict__ bias, float* __restrict__ C, int dil)
{
  int b  = blockIdx.z;
  int n0 = blockIdx.x * 128;
  int t0 = blockIdx.y * 128;
  const float* Xb = X + (size_t)b*T_*256;
  __shared__ _Float16 Ah[128][40], Al[128][40], Wh[128][40], Wl[128][40];
  int tid = threadIdx.x, l = tid & 63, wid = tid >> 6;
  int wr = wid >> 1, wc = wid & 1, lr = l & 15, kg = l >> 4;
  f32x4 acc[4][4];
  #pragma unroll
  for (int m = 0; m < 4; ++m)
    #pragma unroll
    for (int n = 0; n < 4; ++n) acc[m][n] = (f32x4){0.f,0.f,0.f,0.f};

  for (int tap = 0; tap < 3; ++tap) {
    int off = (tap - 1) * dil;
    const float* Wtap = Wt + (size_t)tap*65536;
    for (int k0 = 0; k0 < 256; k0 += 32) {
      #pragma unroll
      for (int i = 0; i < 4; ++i) {
        int q = tid + i*256;
        int row = q >> 3, kq = (q & 7) * 4;
        int rt = t0 + row + off;
        float4 av = make_float4(0.f,0.f,0.f,0.f);
        if ((unsigned)rt < (unsigned)T_)
          av = *(const float4*)(Xb + (size_t)rt*256 + k0 + kq);
        float4 wv = *(const float4*)(Wtap + (size_t)(n0 + row)*256 + k0 + kq);
        half4 hh, ll;
        hh[0]=(_Float16)av.x; ll[0]=(_Float16)(av.x-(float)hh[0]);
        hh[1]=(_Float16)av.y; ll[1]=(_Float16)(av.y-(float)hh[1]);
        hh[2]=(_Float16)av.z; ll[2]=(_Float16)(av.z-(float)hh[2]);
        hh[3]=(_Float16)av.w; ll[3]=(_Float16)(av.w-(float)hh[3]);
        *(half4*)&Ah[row][kq] = hh; *(half4*)&Al[row][kq] = ll;
        hh[0]=(_Float16)wv.x; ll[0]=(_Float16)(wv.x-(float)hh[0]);
        hh[1]=(_Float16)wv.y; ll[1]=(_Float16)(wv.y-(float)hh[1]);
        hh[2]=(_Float16)wv.z; ll[2]=(_Float16)(wv.z-(float)hh[2]);
        hh[3]=(_Float16)wv.w; ll[3]=(_Float16)(wv.w-(float)hh[3]);
        *(half4*)&Wh[row][kq] = hh; *(half4*)&Wl[row][kq] = ll;
      }
      __syncthreads();
      half8 ah[4], al[4], wh[4], wl[4];
      #pragma unroll
      for (int m = 0; m < 4; ++m) {
        ah[m] = *(const half8*)&Ah[wr*64 + m*16 + lr][kg*8];
        al[m] = *(const half8*)&Al[wr*64 + m*16 + lr][kg*8];
      }
      #pragma unroll
      for (int n = 0; n < 4; ++n) {
        wh[n] = *(const half8*)&Wh[wc*64 + n*16 + lr][kg*8];
        wl[n] = *(const half8*)&Wl[wc*64 + n*16 + lr][kg*8];
      }
      #pragma unroll
      for (int m = 0; m < 4; ++m)
        #pragma unroll
        for (int n = 0; n < 4; ++n) {
          acc[m][n] = __builtin_amdgcn_mfma_f32_16x16x32_f16(ah[m], wh[n], acc[m][n], 0, 0, 0);
          acc[m][n] = __builtin_amdgcn_mfma_f32_16x16x32_f16(al[m], wh[n], acc[m][n], 0, 0, 0);
          acc[m][n] = __builtin_amdgcn_mfma_f32_16x16x32_f16(ah[m], wl[n], acc[m][n], 0, 0, 0);
        }
      __syncthreads();
    }
  }
  #pragma unroll
  for (int m = 0; m < 4; ++m)
    #pragma unroll
    for (int n = 0; n < 4; ++n) {
      int col = n0 + wc*64 + n*16 + lr;
      float bi = bias[col];
      #pragma unroll
      for (int r = 0; r < 4; ++r) {
        int row = t0 + wr*64 + m*16 + kg*4 + r;
        size_t off = ((size_t)b*T_ + row)*256 + col;
        C[off] = fmaxf(acc[m][n][r] + bi, 0.f);
      }
    }
}

// ============================================================================
// Instance-norm stats: per (b,f) sum / sumsq over T (atomic partials),
// then finalized in-place to mean / inv-std.
// ============================================================================
__global__ __launch_bounds__(256) void stats_k(
    const float* __restrict__ Xo, float* __restrict__ stats)
{
  int b  = blockIdx.y;
  int t0 = blockIdx.x * (T_/32);
  int f  = threadIdx.x;
  float s = 0.f, s2 = 0.f;
  for (int t = t0; t < t0 + T_/32; ++t) {
    float v = Xo[((size_t)b*T_ + t)*256 + f];
    s += v; s2 += v*v;
  }
  atomicAdd(&stats[b*512 + f], s);
  atomicAdd(&stats[b*512 + 256 + f], s2);
}

__global__ __launch_bounds__(256) void finstats_k(float* __restrict__ stats)
{
  int i = blockIdx.x * 256 + threadIdx.x;   // B*256
  int b = i >> 8, f = i & 255;
  float s  = stats[b*512 + f];
  float s2 = stats[b*512 + 256 + f];
  float m  = s * (1.f/T_);
  float v  = s2 * (1.f/T_) - m*m;
  stats[b*512 + f]       = m;
  stats[b*512 + 256 + f] = rsqrtf(fmaxf(v, 0.f) + 1e-5f);
}

// ============================================================================
// Linear attention pieces (f32)
// ============================================================================
__global__ __launch_bounds__(256) void kv_reduce_k(
    const float* __restrict__ Kb, const float* __restrict__ Vb,
    float* __restrict__ kv)
{
  int bh = blockIdx.y; int b = bh >> 2; int h = bh & 3;
  int t0 = blockIdx.x * (T_/32);           // 256 t's per block
  __shared__ float Ks[64][65];
  __shared__ float Vs[64][65];
  int tid = threadIdx.x;
  int d  = tid >> 2;
  int e0 = (tid & 3) * 16;
  float acc[16] = {};
  float ksum = 0.f;
  int rr = tid >> 4;          // 0..15
  int c4 = (tid & 15) * 4;    // 0..60
  for (int c = 0; c < 4; ++c) {
    int tb = t0 + c*64;
    #pragma unroll
    for (int q = 0; q < 4; ++q) {
      int row = rr + q*16;
      const float* ks = Kb + ((size_t)b*T_ + tb + row)*256 + h*64 + c4;
      const float* vs = Vb + ((size_t)b*T_ + tb + row)*256 + h*64 + c4;
      float4 kvv = *(const float4*)ks;
      float4 vvv = *(const float4*)vs;
      Ks[row][c4]=kvv.x; Ks[row][c4+1]=kvv.y; Ks[row][c4+2]=kvv.z; Ks[row][c4+3]=kvv.w;
      Vs[row][c4]=vvv.x; Vs[row][c4+1]=vvv.y; Vs[row][c4+2]=vvv.z; Vs[row][c4+3]=vvv.w;
    }
    __syncthreads();
    #pragma unroll
    for (int tt = 0; tt < 64; ++tt) {
      float kd = Ks[tt][d];
      if (e0 == 0) ksum += kd;
      #pragma unroll
      for (int j = 0; j < 16; ++j) acc[j] = fmaf(kd, Vs[tt][e0+j], acc[j]);
    }
    __syncthreads();
  }
  float* dst = kv + (size_t)bh*4160;
  #pragma unroll
  for (int j = 0; j < 16; ++j) atomicAdd(&dst[d*64 + e0 + j], acc[j]);
  if (e0 == 0) atomicAdd(&dst[4096 + d], ksum);
}

// o[t,e] = (sum_d Q[t,d]*KV[d,e]) / (sum_d Q[t,d]*(Ksum[d]+1e-6)); O may alias Q
__global__ __launch_bounds__(256) void att_apply_k(
    const float* __restrict__ Qb, const float* __restrict__ kv,
    float* __restrict__ O)
{
  int bh = blockIdx.y; int b = bh >> 2; int h = bh & 3;
  int t0 = blockIdx.x * 64;
  __shared__ float KVs[64][65];
  __shared__ float Qs[64][65];
  __shared__ float ks[64];
  int tid = threadIdx.x;
  const float* src = kv + (size_t)bh*4160;
  #pragma unroll
  for (int i = 0; i < 16; ++i) {
    int idx = tid + i*256;
    KVs[idx >> 6][idx & 63] = src[idx];
  }
  if (tid < 64) ks[tid] = src[4096 + tid] + 1e-6f;
  {
    int r = tid >> 2, c0 = (tid & 3) * 16;
    #pragma unroll
    for (int j = 0; j < 16; j += 4) {
      float4 q = *(const float4*)(Qb + ((size_t)b*T_ + t0 + r)*256 + h*64 + c0 + j);
      Qs[r][c0+j]=q.x; Qs[r][c0+j+1]=q.y; Qs[r][c0+j+2]=q.z; Qs[r][c0+j+3]=q.w;
    }
  }
  __syncthreads();
  int t = tid >> 2, e0 = (tid & 3) * 16;
  float acc[16] = {};
  float den = 0.f;
  #pragma unroll 4
  for (int dd = 0; dd < 64; ++dd) {
    float qv = Qs[t][dd];
    den = fmaf(qv, ks[dd], den);
    #pragma unroll
    for (int j = 0; j < 16; ++j) acc[j] = fmaf(qv, KVs[dd][e0+j], acc[j]);
  }
  float z = 1.f / den;
  float* dst = O + ((size_t)b*T_ + t0 + t)*256 + h*64 + e0;
  #pragma unroll
  for (int j = 0; j < 16; ++j) dst[j] = acc[j] * z;
}

// ============================================================================
// SFI gram: G[b,c,d] += sum over t-chunk of A[b,t,c]*B[b,t,d]
// t-chunk 256 (grid.x=32) so 2 blocks/CU are resident for latency hiding.
// ============================================================================
__global__ __launch_bounds__(256) void gram_k(
    const float* __restrict__ Ab, const float* __restrict__ Bb,
    float* __restrict__ G)
{
  int b  = blockIdx.z;
  int c0 = (blockIdx.y >> 1) * 128;
  int d0 = (blockIdx.y & 1) * 128;
  int t0 = blockIdx.x * (T_/32);   // 256 t's
  __shared__ float As[8][132];
  __shared__ float Bs[8][132];
  int tid = threadIdx.x, tx = tid & 15, ty = tid >> 4;
  int kk = tid >> 5;          // 0..7
  int cc = (tid & 31) * 4;    // 0..124
  float acc[8][8] = {};
  for (int k0 = 0; k0 < 256; k0 += 8) {
    size_t row = ((size_t)b*T_ + t0 + k0 + kk) * 256;
    float4 av = *(const float4*)(Ab + row + c0 + cc);
    float4 bv = *(const float4*)(Bb + row + d0 + cc);
    As[kk][cc]=av.x; As[kk][cc+1]=av.y; As[kk][cc+2]=av.z; As[kk][cc+3]=av.w;
    Bs[kk][cc]=bv.x; Bs[kk][cc+1]=bv.y; Bs[kk][cc+2]=bv.z; Bs[kk][cc+3]=bv.w;
    __syncthreads();
    #pragma unroll
    for (int q = 0; q < 8; ++q) {
      float a[8], w[8];
      #pragma unroll
      for (int i = 0; i < 8; ++i) a[i] = As[q][ty*8 + i];
      #pragma unroll
      for (int j = 0; j < 8; ++j) w[j] = Bs[q][tx*8 + j];
      #pragma unroll
      for (int i = 0; i < 8; ++i)
        #pragma unroll
        for (int j = 0; j < 8; ++j)
          acc[i][j] = fmaf(a[i], w[j], acc[i][j]);
    }
    __syncthreads();
  }
  #pragma unroll
  for (int i = 0; i < 8; ++i)
    #pragma unroll
    for (int j = 0; j < 8; ++j)
      atomicAdd(&G[((size_t)b << 16) + (size_t)(c0 + ty*8 + i)*256 + d0 + tx*8 + j],
                acc[i][j]);
}

// softmax over rows of G (1024 rows of 256), with pre-scale 1/T
__global__ __launch_bounds__(64) void softmax_k(float* __restrict__ G)
{
  int row = blockIdx.x;
  float* p = G + (size_t)row * 256;
  int l = threadIdx.x;
  float v[4];
  float mx = -1e30f;
  #pragma unroll
  for (int j = 0; j < 4; ++j) { v[j] = p[l*4 + j] * (1.f/T_); mx = fmaxf(mx, v[j]); }
  #pragma unroll
  for (int off = 32; off > 0; off >>= 1) mx = fmaxf(mx, __shfl_xor(mx, off));
  float s = 0.f;
  #pragma unroll
  for (int j = 0; j < 4; ++j) { v[j] = expf(v[j] - mx); s += v[j]; }
  #pragma unroll
  for (int off = 32; off > 0; off >>= 1) s += __shfl_xor(s, off);
  float inv = 1.f / s;
  #pragma unroll
  for (int j = 0; j < 4; ++j) p[l*4 + j] = v[j] * inv;
}

// ============================================================================
// Final: out[b,o,t] = (sum_c fst[b,t,c]*Wn[o,c] + bn[o]) * mask[b,t]
// ============================================================================
__global__ __launch_bounds__(256) void final_k(
    const float* __restrict__ A, const float* __restrict__ Wn,
    const float* __restrict__ bn, const float* __restrict__ mask,
    float* __restrict__ out)
{
  int b = blockIdx.y, t0 = blockIdx.x * 32;
  __shared__ float As[32][257];
  int tid = threadIdx.x;
  #pragma unroll
  for (int i = 0; i < 8; ++i) {
    int f4 = tid + i*256;            // 0..2047
    int rr = f4 >> 6;
    int c4 = (f4 & 63) * 4;
    float4 v = *(const float4*)(A + ((size_t)b*T_ + t0 + rr)*256 + c4);
    As[rr][c4]=v.x; As[rr][c4+1]=v.y; As[rr][c4+2]=v.z; As[rr][c4+3]=v.w;
  }
  __syncthreads();
  int t  = tid & 31;
  int og = tid >> 5;                 // 8 groups x 6 outputs
  float m = mask[(size_t)b*T_ + t0 + t];
  for (int o = og*6; o < og*6 + 6; ++o) {
    float acc = bn[o];
    const float* wr = Wn + o*256;
    #pragma unroll 8
    for (int c = 0; c < 256; ++c) acc = fmaf(As[t][c], wr[c], acc);
    out[((size_t)b*48 + o)*T_ + t0 + t] = acc * m;
  }
}

// ============================================================================
extern "C" void kernel_launch(void* const* d_in, const int* in_sizes, int n_in,
                              void* d_out, int out_size, void* d_ws, size_t ws_size,
                              hipStream_t stream) {
  const float* x         = (const float*)d_in[0];
  const float* mask      = (const float*)d_in[1];
  const float* conv_in_w = (const float*)d_in[2];
  const float* conv_in_b = (const float*)d_in[3];
  const float* conv_t_w  = (const float*)d_in[4];
  const float* conv_t_b  = (const float*)d_in[5];
  const float* sfi_cs_w  = (const float*)d_in[6];
  const float* sfi_cs_b  = (const float*)d_in[7];
  const float* sfi_ff1_w = (const float*)d_in[8];
  const float* sfi_ff1_b = (const float*)d_in[9];
  const float* sfi_ff2_w = (const float*)d_in[10];
  const float* sfi_ff2_b = (const float*)d_in[11];
  const float* ff_w      = (const float*)d_in[12];
  const float* ff_b      = (const float*)d_in[13];
  const float* qw = (const float*)d_in[14]; const float* qb = (const float*)d_in[15];
  const float* kw = (const float*)d_in[16]; const float* kb = (const float*)d_in[17];
  const float* vw = (const float*)d_in[18]; const float* vb = (const float*)d_in[19];
  const float* ow = (const float*)d_in[20]; const float* ob = (const float*)d_in[21];
  const float* co_w = (const float*)d_in[22]; const float* co_b = (const float*)d_in[23];
  const float* out_w = (const float*)d_in[24]; const float* out_b = (const float*)d_in[25];

  float* ws = (float*)d_ws;
  const size_t BT = (size_t)B_ * T_;
  // ---- workspace layout (floats) ---- total ~44.4M floats = 178 MB
  float* small = ws;                        // BT*64 (xi5 / per-SFI fs / conv-W)
  float* fstA  = small + BT*64;             // BT*256
  float* fstB  = fstA + BT*256;
  float* Tb1   = fstB + BT*256;
  float* Tb2   = Tb1 + BT*256;
  float* Tb3   = Tb2 + BT*256;
  float* gram  = Tb3 + BT*256;              // B*256*256
  float* stats = gram + (size_t)B_*256*256; // B*512
  float* kvbuf = stats + B_*512;            // 16*4160
  float* cwt   = small;                     // 3*256*256 fits in small (2.1M)

  dim3 gh(2, T_/128, B_);                   // x=n-block so A-sharers adjacent
  dim3 b256(256);

  init_k<<<dim3((unsigned)(BT*64/256)), b256, 0, stream>>>(x, conv_in_w, conv_in_b, small);
  gemm_h<0,0><<<gh, b256, 0, stream>>>(small, conv_t_w, conv_t_b, nullptr, fstA,
                                       64, 0, nullptr);

  float* fst  = fstA;
  float* fstN = fstB;
  int count = 0;
  for (int i = 0; i < 10; ++i) {
    if (i == 1 || i == 3 || i == 5 || i == 7) {
      // ---- SFI ----
      fs_k<<<dim3((unsigned)(BT*64/256)), b256, 0, stream>>>(x, conv_in_w, conv_in_b, small, count);
      gemm_h<0,0><<<gh, b256, 0, stream>>>(small, sfi_cs_w + (size_t)count*256*64,
                                           sfi_cs_b + count*256, nullptr, Tb1,
                                           64, 0, nullptr);
      hipMemsetAsync(gram, 0, (size_t)B_*256*256*sizeof(float), stream);
      gram_k<<<dim3(32, 4, B_), b256, 0, stream>>>(Tb1, fst, gram);
      softmax_k<<<dim3(B_*256), dim3(64), 0, stream>>>(gram);
      gemm_h<0,0><<<gh, b256, 0, stream>>>(fst, gram, nullptr, fst, Tb2,
                                           256, (size_t)256*256, nullptr);
      gemm_h<3,0><<<gh, b256, 0, stream>>>(Tb2, sfi_ff1_w + (size_t)count*256*256,
                                           sfi_ff1_b + count*256, nullptr, Tb3,
                                           256, 0, nullptr);
      gemm_h<0,0><<<gh, b256, 0, stream>>>(Tb3, sfi_ff2_w + (size_t)count*256*256,
                                           sfi_ff2_b + count*256, fst, fstN,
                                           256, 0, nullptr);
      float* tmp = fst; fst = fstN; fstN = tmp;
      ++count;
    }
    // ---- attention module ----
    int dil = 1 << i;
    convw_prep_k<<<dim3(768), b256, 0, stream>>>(ff_w + (size_t)i*256*256*3, cwt);
    conv_h<<<gh, b256, 0, stream>>>(fst, cwt, ff_b + i*256, fstN, dil);
    hipMemsetAsync(stats, 0, (size_t)B_*512*sizeof(float), stream);
    stats_k<<<dim3(32, B_), b256, 0, stream>>>(fstN, stats);
    finstats_k<<<dim3(B_), b256, 0, stream>>>(stats);
    gemm_h<2,1><<<gh, b256, 0, stream>>>(fstN, qw + (size_t)i*256*256, qb + i*256,
                                         nullptr, Tb1, 256, 0, stats);
    gemm_h<2,1><<<gh, b256, 0, stream>>>(fstN, kw + (size_t)i*256*256, kb + i*256,
                                         nullptr, Tb2, 256, 0, stats);
    gemm_h<0,1><<<gh, b256, 0, stream>>>(fstN, vw + (size_t)i*256*256, vb + i*256,
                                         nullptr, Tb3, 256, 0, stats);
    hipMemsetAsync(kvbuf, 0, (size_t)16*4160*sizeof(float), stream);
    kv_reduce_k<<<dim3(32, 16), b256, 0, stream>>>(Tb2, Tb3, kvbuf);
    att_apply_k<<<dim3(T_/64, 16), b256, 0, stream>>>(Tb1, kvbuf, Tb1);   // in-place
    gemm_h<0,0><<<gh, b256, 0, stream>>>(Tb1, ow + (size_t)i*256*256, ob + i*256,
                                         fstN, Tb2, 256, 0, nullptr);
    gemm_h<0,0><<<gh, b256, 0, stream>>>(Tb2, co_w + (size_t)i*256*256, co_b + i*256,
                                         fst, fstN, 256, 0, nullptr);
    float* tmp = fst; fst = fstN; fstN = tmp;
  }
  final_k<<<dim3(T_/32, B_), b256, 0, stream>>>(fst, out_w, out_b, mask, (float*)d_out);
}

// Round 4
// 4283.821 us; speedup vs baseline: 2.4584x; 1.7509x over previous
//
#include <hip/hip_runtime.h>

#define T_ 8192
#define B_ 4

typedef _Float16 half4 __attribute__((ext_vector_type(4)));
typedef _Float16 half8 __attribute__((ext_vector_type(8)));
typedef float    f32x4 __attribute__((ext_vector_type(4)));

__device__ __forceinline__ void split2(float v, _Float16* hp, _Float16* lp) {
  _Float16 h = (_Float16)v;
  *hp = h; *lp = (_Float16)(v - (float)h);
}

// ============================================================================
// init: xi5[b,t,n] = sum_i x[b,i,t,n]*cw[4,i] + cb[4]
// ============================================================================
__global__ __launch_bounds__(256) void init_k(
    const float* __restrict__ x, const float* __restrict__ cw,
    const float* __restrict__ cb, float* __restrict__ xi5)
{
  size_t idx = (size_t)blockIdx.x * 256 + threadIdx.x;   // over B*T*64
  int n = (int)(idx & 63);
  int t = (int)((idx >> 6) & (T_ - 1));
  int b = (int)(idx >> 19);
  float x0 = x[(((size_t)b*3 + 0)*T_ + t)*64 + n];
  float x1 = x[(((size_t)b*3 + 1)*T_ + t)*64 + n];
  float x2 = x[(((size_t)b*3 + 2)*T_ + t)*64 + n];
  xi5[idx] = cb[4] + x0*cw[12] + x1*cw[13] + x2*cw[14];
}

__global__ __launch_bounds__(256) void fs_k(
    const float* __restrict__ x, const float* __restrict__ cw,
    const float* __restrict__ cb, float* __restrict__ fs, int c)
{
  size_t idx = (size_t)blockIdx.x * 256 + threadIdx.x;
  int n = (int)(idx & 63);
  int t = (int)((idx >> 6) & (T_ - 1));
  int b = (int)(idx >> 19);
  float x0 = x[(((size_t)b*3 + 0)*T_ + t)*64 + n];
  float x1 = x[(((size_t)b*3 + 1)*T_ + t)*64 + n];
  float x2 = x[(((size_t)b*3 + 2)*T_ + t)*64 + n];
  fs[idx] = cb[c] + x0*cw[c*3] + x1*cw[c*3+1] + x2*cw[c*3+2];
}

// conv weight transpose: src[n][k][tap] -> dst[tap][n][k]
__global__ __launch_bounds__(256) void convw_prep_k(
    const float* __restrict__ src, float* __restrict__ dst)
{
  int idx = blockIdx.x*256 + threadIdx.x;   // 3*256*256
  int k = idx & 255, n = (idx >> 8) & 255, tap = idx >> 16;
  dst[idx] = src[(((size_t)n << 8) + k)*3 + tap];
  (void)tap;
}

// ============================================================================
// fp16x2 split-precision MFMA GEMM (D = Ah*Wh + Al*Wh + Ah*Wl), N=256.
// ============================================================================
template<int ACT, int NORM>
__global__ __launch_bounds__(256, 2) void gemm_h(
    const float* __restrict__ A, const float* __restrict__ W,
    const float* __restrict__ bias, const float* __restrict__ resid,
    float* __restrict__ C, int K, size_t wbs,
    const float* __restrict__ stats2)
{
  int b  = blockIdx.z;
  int n0 = blockIdx.x * 128;
  int t0 = blockIdx.y * 128;
  const float* Ab = A + (size_t)b*T_*K;
  const float* Wb = W + (size_t)b*wbs;
  const float* st = NORM ? (stats2 + b*512) : nullptr;
  __shared__ _Float16 Ah[128][40], Al[128][40], Wh[128][40], Wl[128][40];
  int tid = threadIdx.x, l = tid & 63, wid = tid >> 6;
  int wr = wid >> 1, wc = wid & 1, lr = l & 15, kg = l >> 4;
  f32x4 acc[4][4];
  #pragma unroll
  for (int m = 0; m < 4; ++m)
    #pragma unroll
    for (int n = 0; n < 4; ++n) acc[m][n] = (f32x4){0.f,0.f,0.f,0.f};

  for (int k0 = 0; k0 < K; k0 += 32) {
    #pragma unroll
    for (int i = 0; i < 4; ++i) {
      int q = tid + i*256;
      int row = q >> 3, kq = (q & 7) * 4;
      float4 av = *(const float4*)(Ab + (size_t)(t0 + row)*K + k0 + kq);
      if (NORM) {
        av.x = (av.x - st[k0+kq+0]) * st[256+k0+kq+0];
        av.y = (av.y - st[k0+kq+1]) * st[256+k0+kq+1];
        av.z = (av.z - st[k0+kq+2]) * st[256+k0+kq+2];
        av.w = (av.w - st[k0+kq+3]) * st[256+k0+kq+3];
      }
      float4 wv = *(const float4*)(Wb + (size_t)(n0 + row)*K + k0 + kq);
      split2(av.x, &Ah[row][kq+0], &Al[row][kq+0]);
      split2(av.y, &Ah[row][kq+1], &Al[row][kq+1]);
      split2(av.z, &Ah[row][kq+2], &Al[row][kq+2]);
      split2(av.w, &Ah[row][kq+3], &Al[row][kq+3]);
      split2(wv.x, &Wh[row][kq+0], &Wl[row][kq+0]);
      split2(wv.y, &Wh[row][kq+1], &Wl[row][kq+1]);
      split2(wv.z, &Wh[row][kq+2], &Wl[row][kq+2]);
      split2(wv.w, &Wh[row][kq+3], &Wl[row][kq+3]);
    }
    __syncthreads();
    half8 ah[4], al[4], wh[4], wl[4];
    #pragma unroll
    for (int m = 0; m < 4; ++m) {
      ah[m] = *(const half8*)&Ah[wr*64 + m*16 + lr][kg*8];
      al[m] = *(const half8*)&Al[wr*64 + m*16 + lr][kg*8];
    }
    #pragma unroll
    for (int n = 0; n < 4; ++n) {
      wh[n] = *(const half8*)&Wh[wc*64 + n*16 + lr][kg*8];
      wl[n] = *(const half8*)&Wl[wc*64 + n*16 + lr][kg*8];
    }
    #pragma unroll
    for (int m = 0; m < 4; ++m)
      #pragma unroll
      for (int n = 0; n < 4; ++n) {
        acc[m][n] = __builtin_amdgcn_mfma_f32_16x16x32_f16(ah[m], wh[n], acc[m][n], 0, 0, 0);
        acc[m][n] = __builtin_amdgcn_mfma_f32_16x16x32_f16(al[m], wh[n], acc[m][n], 0, 0, 0);
        acc[m][n] = __builtin_amdgcn_mfma_f32_16x16x32_f16(ah[m], wl[n], acc[m][n], 0, 0, 0);
      }
    __syncthreads();
  }
  #pragma unroll
  for (int m = 0; m < 4; ++m)
    #pragma unroll
    for (int n = 0; n < 4; ++n) {
      int col = n0 + wc*64 + n*16 + lr;
      float bi = bias ? bias[col] : 0.f;
      #pragma unroll
      for (int r = 0; r < 4; ++r) {
        int row = t0 + wr*64 + m*16 + kg*4 + r;
        size_t off = ((size_t)b*T_ + row)*256 + col;
        float v = acc[m][n][r] + bi;
        if (ACT == 1) v = fmaxf(v, 0.f);
        if (ACT == 2) v = 1.f/(1.f + expf(-v));
        if (ACT == 3) v = 0.5f*v*(1.f + erff(v*0.7071067811865475f));
        if (resid) v += resid[off];
        C[off] = v;
      }
    }
}

// ============================================================================
// Fused Q/K/V projection with instance-norm on A. grid (6, T/128, B).
// ============================================================================
__global__ __launch_bounds__(256, 2) void gemm_qkv_k(
    const float* __restrict__ A,
    const float* __restrict__ Wq, const float* __restrict__ Wk, const float* __restrict__ Wv,
    const float* __restrict__ bq, const float* __restrict__ bk, const float* __restrict__ bv,
    float* __restrict__ Q, float* __restrict__ Ko, float* __restrict__ V,
    const float* __restrict__ stats2)
{
  int b   = blockIdx.z;
  int sel = blockIdx.x >> 1;
  int n0  = (blockIdx.x & 1) * 128;
  int t0  = blockIdx.y * 128;
  const float* W    = sel == 0 ? Wq : (sel == 1 ? Wk : Wv);
  const float* bias = sel == 0 ? bq : (sel == 1 ? bk : bv);
  float*       C    = sel == 0 ? Q  : (sel == 1 ? Ko : V);
  const float* Ab = A + (size_t)b*T_*256;
  const float* st = stats2 + b*512;
  __shared__ _Float16 Ah[128][40], Al[128][40], Wh[128][40], Wl[128][40];
  int tid = threadIdx.x, l = tid & 63, wid = tid >> 6;
  int wr = wid >> 1, wc = wid & 1, lr = l & 15, kg = l >> 4;
  f32x4 acc[4][4];
  #pragma unroll
  for (int m = 0; m < 4; ++m)
    #pragma unroll
    for (int n = 0; n < 4; ++n) acc[m][n] = (f32x4){0.f,0.f,0.f,0.f};

  for (int k0 = 0; k0 < 256; k0 += 32) {
    #pragma unroll
    for (int i = 0; i < 4; ++i) {
      int q = tid + i*256;
      int row = q >> 3, kq = (q & 7) * 4;
      float4 av = *(const float4*)(Ab + (size_t)(t0 + row)*256 + k0 + kq);
      av.x = (av.x - st[k0+kq+0]) * st[256+k0+kq+0];
      av.y = (av.y - st[k0+kq+1]) * st[256+k0+kq+1];
      av.z = (av.z - st[k0+kq+2]) * st[256+k0+kq+2];
      av.w = (av.w - st[k0+kq+3]) * st[256+k0+kq+3];
      float4 wv = *(const float4*)(W + (size_t)(n0 + row)*256 + k0 + kq);
      split2(av.x, &Ah[row][kq+0], &Al[row][kq+0]);
      split2(av.y, &Ah[row][kq+1], &Al[row][kq+1]);
      split2(av.z, &Ah[row][kq+2], &Al[row][kq+2]);
      split2(av.w, &Ah[row][kq+3], &Al[row][kq+3]);
      split2(wv.x, &Wh[row][kq+0], &Wl[row][kq+0]);
      split2(wv.y, &Wh[row][kq+1], &Wl[row][kq+1]);
      split2(wv.z, &Wh[row][kq+2], &Wl[row][kq+2]);
      split2(wv.w, &Wh[row][kq+3], &Wl[row][kq+3]);
    }
    __syncthreads();
    half8 ah[4], al[4], wh[4], wl[4];
    #pragma unroll
    for (int m = 0; m < 4; ++m) {
      ah[m] = *(const half8*)&Ah[wr*64 + m*16 + lr][kg*8];
      al[m] = *(const half8*)&Al[wr*64 + m*16 + lr][kg*8];
    }
    #pragma unroll
    for (int n = 0; n < 4; ++n) {
      wh[n] = *(const half8*)&Wh[wc*64 + n*16 + lr][kg*8];
      wl[n] = *(const half8*)&Wl[wc*64 + n*16 + lr][kg*8];
    }
    #pragma unroll
    for (int m = 0; m < 4; ++m)
      #pragma unroll
      for (int n = 0; n < 4; ++n) {
        acc[m][n] = __builtin_amdgcn_mfma_f32_16x16x32_f16(ah[m], wh[n], acc[m][n], 0, 0, 0);
        acc[m][n] = __builtin_amdgcn_mfma_f32_16x16x32_f16(al[m], wh[n], acc[m][n], 0, 0, 0);
        acc[m][n] = __builtin_amdgcn_mfma_f32_16x16x32_f16(ah[m], wl[n], acc[m][n], 0, 0, 0);
      }
    __syncthreads();
  }
  #pragma unroll
  for (int m = 0; m < 4; ++m)
    #pragma unroll
    for (int n = 0; n < 4; ++n) {
      int col = n0 + wc*64 + n*16 + lr;
      float bi = bias[col];
      #pragma unroll
      for (int r = 0; r < 4; ++r) {
        int row = t0 + wr*64 + m*16 + kg*4 + r;
        size_t off = ((size_t)b*T_ + row)*256 + col;
        float v = acc[m][n][r] + bi;
        if (sel < 2) v = 1.f/(1.f + expf(-v));
        C[off] = v;
      }
    }
}

// ============================================================================
// Dilated conv as 3-tap accumulated fp16x2 MFMA GEMM. Wt: [tap][n][k] f32.
// ============================================================================
__global__ __launch_bounds__(256, 2) void conv_h(
    const float* __restrict__ X, const float* __restrict__ Wt,
    const float* __restrict__ bias, float* __restrict__ C, int dil)
{
  int b  = blockIdx.z;
  int n0 = blockIdx.x * 128;
  int t0 = blockIdx.y * 128;
  const float* Xb = X + (size_t)b*T_*256;
  __shared__ _Float16 Ah[128][40], Al[128][40], Wh[128][40], Wl[128][40];
  int tid = threadIdx.x, l = tid & 63, wid = tid >> 6;
  int wr = wid >> 1, wc = wid & 1, lr = l & 15, kg = l >> 4;
  f32x4 acc[4][4];
  #pragma unroll
  for (int m = 0; m < 4; ++m)
    #pragma unroll
    for (int n = 0; n < 4; ++n) acc[m][n] = (f32x4){0.f,0.f,0.f,0.f};

  for (int tap = 0; tap < 3; ++tap) {
    int off = (tap - 1) * dil;
    const float* Wtap = Wt + (size_t)tap*65536;
    for (int k0 = 0; k0 < 256; k0 += 32) {
      #pragma unroll
      for (int i = 0; i < 4; ++i) {
        int q = tid + i*256;
        int row = q >> 3, kq = (q & 7) * 4;
        int rt = t0 + row + off;
        float4 av = make_float4(0.f,0.f,0.f,0.f);
        if ((unsigned)rt < (unsigned)T_)
          av = *(const float4*)(Xb + (size_t)rt*256 + k0 + kq);
        float4 wv = *(const float4*)(Wtap + (size_t)(n0 + row)*256 + k0 + kq);
        split2(av.x, &Ah[row][kq+0], &Al[row][kq+0]);
        split2(av.y, &Ah[row][kq+1], &Al[row][kq+1]);
        split2(av.z, &Ah[row][kq+2], &Al[row][kq+2]);
        split2(av.w, &Ah[row][kq+3], &Al[row][kq+3]);
        split2(wv.x, &Wh[row][kq+0], &Wl[row][kq+0]);
        split2(wv.y, &Wh[row][kq+1], &Wl[row][kq+1]);
        split2(wv.z, &Wh[row][kq+2], &Wl[row][kq+2]);
        split2(wv.w, &Wh[row][kq+3], &Wl[row][kq+3]);
      }
      __syncthreads();
      half8 ah[4], al[4], wh[4], wl[4];
      #pragma unroll
      for (int m = 0; m < 4; ++m) {
        ah[m] = *(const half8*)&Ah[wr*64 + m*16 + lr][kg*8];
        al[m] = *(const half8*)&Al[wr*64 + m*16 + lr][kg*8];
      }
      #pragma unroll
      for (int n = 0; n < 4; ++n) {
        wh[n] = *(const half8*)&Wh[wc*64 + n*16 + lr][kg*8];
        wl[n] = *(const half8*)&Wl[wc*64 + n*16 + lr][kg*8];
      }
      #pragma unroll
      for (int m = 0; m < 4; ++m)
        #pragma unroll
        for (int n = 0; n < 4; ++n) {
          acc[m][n] = __builtin_amdgcn_mfma_f32_16x16x32_f16(ah[m], wh[n], acc[m][n], 0, 0, 0);
          acc[m][n] = __builtin_amdgcn_mfma_f32_16x16x32_f16(al[m], wh[n], acc[m][n], 0, 0, 0);
          acc[m][n] = __builtin_amdgcn_mfma_f32_16x16x32_f16(ah[m], wl[n], acc[m][n], 0, 0, 0);
        }
      __syncthreads();
    }
  }
  #pragma unroll
  for (int m = 0; m < 4; ++m)
    #pragma unroll
    for (int n = 0; n < 4; ++n) {
      int col = n0 + wc*64 + n*16 + lr;
      float bi = bias[col];
      #pragma unroll
      for (int r = 0; r < 4; ++r) {
        int row = t0 + wr*64 + m*16 + kg*4 + r;
        size_t off = ((size_t)b*T_ + row)*256 + col;
        C[off] = fmaxf(acc[m][n][r] + bi, 0.f);
      }
    }
}

// ============================================================================
// Instance-norm stats
// ============================================================================
__global__ __launch_bounds__(256) void stats_k(
    const float* __restrict__ Xo, float* __restrict__ stats)
{
  int b  = blockIdx.y;
  int t0 = blockIdx.x * (T_/32);
  int f  = threadIdx.x;
  float s = 0.f, s2 = 0.f;
  for (int t = t0; t < t0 + T_/32; ++t) {
    float v = Xo[((size_t)b*T_ + t)*256 + f];
    s += v; s2 += v*v;
  }
  atomicAdd(&stats[b*512 + f], s);
  atomicAdd(&stats[b*512 + 256 + f], s2);
}

__global__ __launch_bounds__(256) void finstats_k(float* __restrict__ stats)
{
  int i = blockIdx.x * 256 + threadIdx.x;   // B*256
  int b = i >> 8, f = i & 255;
  float s  = stats[b*512 + f];
  float s2 = stats[b*512 + 256 + f];
  float m  = s * (1.f/T_);
  float v  = s2 * (1.f/T_) - m*m;
  stats[b*512 + f]       = m;
  stats[b*512 + 256 + f] = rsqrtf(fmaxf(v, 0.f) + 1e-5f);
}

// ============================================================================
// kv partial: per (chunk, bh) block computes KV[d,e] & Ksum[d] over 512 t.
// grid (16, 16), block 256. No atomics: wave partials -> LDS reduce -> pkv.
// ============================================================================
__global__ __launch_bounds__(256) void kv_part_k(
    const float* __restrict__ Kb, const float* __restrict__ Vb,
    float* __restrict__ pkv)
{
  int bh = blockIdx.y, b = bh >> 2, h = bh & 3;
  int t0 = blockIdx.x * 512;
  __shared__ float Ks[64][68];
  __shared__ float Vs[64][68];
  __shared__ float ksred[64];
  int tid = threadIdx.x;
  int wv = tid >> 6;
  int dq = (tid >> 2) & 15;
  int e4 = tid & 3, e0 = e4 * 16;
  float acc[4][16] = {};
  float ks4[4] = {};
  for (int w = 0; w < 8; ++w) {
    #pragma unroll
    for (int i = 0; i < 4; ++i) {
      int q = tid + i*256;
      int r = q >> 4;
      int c4 = (q & 15) * 4;
      size_t off = ((size_t)b*T_ + t0 + w*64 + r)*256 + h*64 + c4;
      *(float4*)&Ks[r][c4] = *(const float4*)(Kb + off);
      *(float4*)&Vs[r][c4] = *(const float4*)(Vb + off);
    }
    __syncthreads();
    #pragma unroll 4
    for (int tt = wv*16; tt < wv*16 + 16; ++tt) {
      float4 k4 = *(const float4*)&Ks[tt][dq*4];
      if (e4 == 0) {
        ks4[0] += k4.x; ks4[1] += k4.y; ks4[2] += k4.z; ks4[3] += k4.w;
      }
      float va[16];
      *(float4*)&va[0]  = *(const float4*)&Vs[tt][e0+0];
      *(float4*)&va[4]  = *(const float4*)&Vs[tt][e0+4];
      *(float4*)&va[8]  = *(const float4*)&Vs[tt][e0+8];
      *(float4*)&va[12] = *(const float4*)&Vs[tt][e0+12];
      float ka[4] = {k4.x, k4.y, k4.z, k4.w};
      #pragma unroll
      for (int i = 0; i < 4; ++i)
        #pragma unroll
        for (int j = 0; j < 16; ++j)
          acc[i][j] = fmaf(ka[i], va[j], acc[i][j]);
    }
    __syncthreads();
  }
  // sequential wave reduce into Ks (reused as f32 KV[64][<=68]) + ksred
  if (wv == 0) {
    #pragma unroll
    for (int i = 0; i < 4; ++i) {
      #pragma unroll
      for (int j = 0; j < 16; ++j) Ks[dq*4+i][e0+j] = acc[i][j];
      if (e4 == 0) ksred[dq*4+i] = ks4[i];
    }
  }
  __syncthreads();
  if (wv == 1) {
    #pragma unroll
    for (int i = 0; i < 4; ++i) {
      #pragma unroll
      for (int j = 0; j < 16; ++j) Ks[dq*4+i][e0+j] += acc[i][j];
      if (e4 == 0) ksred[dq*4+i] += ks4[i];
    }
  }
  __syncthreads();
  if (wv == 2) {
    #pragma unroll
    for (int i = 0; i < 4; ++i) {
      #pragma unroll
      for (int j = 0; j < 16; ++j) Ks[dq*4+i][e0+j] += acc[i][j];
      if (e4 == 0) ksred[dq*4+i] += ks4[i];
    }
  }
  __syncthreads();
  if (wv == 3) {
    #pragma unroll
    for (int i = 0; i < 4; ++i) {
      #pragma unroll
      for (int j = 0; j < 16; ++j) Ks[dq*4+i][e0+j] += acc[i][j];
      if (e4 == 0) ksred[dq*4+i] += ks4[i];
    }
  }
  __syncthreads();
  float* dst = pkv + ((size_t)blockIdx.x*16 + bh)*4160;
  #pragma unroll
  for (int i = 0; i < 16; ++i) {
    int idx = tid + i*256;
    dst[idx] = Ks[idx >> 6][idx & 63];
  }
  if (tid < 64) dst[4096 + tid] = ksred[tid];
}

__global__ __launch_bounds__(256) void kv_final_k(
    const float* __restrict__ pkv, float* __restrict__ kv)
{
  int bh = blockIdx.x;
  for (int idx = threadIdx.x; idx < 4160; idx += 256) {
    float s = 0.f;
    #pragma unroll
    for (int c = 0; c < 16; ++c) s += pkv[((size_t)c*16 + bh)*4160 + idx];
    kv[(size_t)bh*4160 + idx] = s;
  }
}

// ============================================================================
// att apply: o[t,e] = (sum_d Q[t,d]*KV[d,e]) / (sum_d Q[t,d]*(Ksum[d]+1e-6))
// Transposed Q in LDS, t-pair register tiling. O may alias Qb (block-local).
// grid (T/128, 16).
// ============================================================================
__global__ __launch_bounds__(256) void att_apply_k(
    const float* __restrict__ Qb, const float* __restrict__ kv,
    float* __restrict__ O)
{
  int bh = blockIdx.y, b = bh >> 2, h = bh & 3;
  int t0 = blockIdx.x * 128;
  __shared__ float QsT[64][132];
  __shared__ float KVs[64][68];
  __shared__ float ks[64];
  int tid = threadIdx.x;
  const float* src = kv + (size_t)bh*4160;
  #pragma unroll
  for (int i = 0; i < 16; ++i) {
    int idx = tid + i*256;
    KVs[idx >> 6][idx & 63] = src[idx];
  }
  if (tid < 64) ks[tid] = src[4096 + tid] + 1e-6f;
  #pragma unroll
  for (int i = 0; i < 8; ++i) {
    int q4 = tid + i*256;      // 0..2047
    int t  = q4 >> 4;          // 0..127
    int d4 = (q4 & 15) * 4;
    float4 v = *(const float4*)(Qb + ((size_t)b*T_ + t0 + t)*256 + h*64 + d4);
    QsT[d4+0][t] = v.x; QsT[d4+1][t] = v.y;
    QsT[d4+2][t] = v.z; QsT[d4+3][t] = v.w;
  }
  __syncthreads();
  int t2 = (tid >> 2) * 2;
  int e0 = (tid & 3) * 16;
  float acc[2][16] = {};
  float den[2] = {};
  for (int dd = 0; dd < 64; ++dd) {
    float2 q = *(const float2*)&QsT[dd][t2];
    float kd = ks[dd];
    den[0] = fmaf(q.x, kd, den[0]);
    den[1] = fmaf(q.y, kd, den[1]);
    float va[16];
    *(float4*)&va[0]  = *(const float4*)&KVs[dd][e0+0];
    *(float4*)&va[4]  = *(const float4*)&KVs[dd][e0+4];
    *(float4*)&va[8]  = *(const float4*)&KVs[dd][e0+8];
    *(float4*)&va[12] = *(const float4*)&KVs[dd][e0+12];
    #pragma unroll
    for (int j = 0; j < 16; ++j) {
      acc[0][j] = fmaf(q.x, va[j], acc[0][j]);
      acc[1][j] = fmaf(q.y, va[j], acc[1][j]);
    }
  }
  #pragma unroll
  for (int ti = 0; ti < 2; ++ti) {
    float z = 1.f / den[ti];
    float* dst = O + ((size_t)b*T_ + t0 + t2 + ti)*256 + h*64 + e0;
    #pragma unroll
    for (int j = 0; j < 16; j += 4) {
      float4 v = make_float4(acc[ti][j]*z, acc[ti][j+1]*z, acc[ti][j+2]*z, acc[ti][j+3]*z);
      *(float4*)(dst + j) = v;
    }
  }
}

// ============================================================================
// SFI gram partial via fp16x2 MFMA: G_slab[c,d] = sum over t-slab A[t,c]B[t,d]
// grid (16 slabs, 4 quads, B). Transposed LDS staging ([c][t]).
// ============================================================================
__global__ __launch_bounds__(256, 2) void gram_part_k(
    const float* __restrict__ Ab, const float* __restrict__ Bb,
    float* __restrict__ pg)
{
  int b = blockIdx.z;
  int quad = blockIdx.y;
  int slab = blockIdx.x;
  int c0 = (quad >> 1) * 128, d0 = (quad & 1) * 128;
  int t0 = slab * 512;
  __shared__ _Float16 Ah[128][40], Al[128][40], Bh[128][40], Bl[128][40];
  int tid = threadIdx.x, l = tid & 63, wid = tid >> 6;
  int wr = wid >> 1, wc = wid & 1, lr = l & 15, kg = l >> 4;
  f32x4 acc[4][4];
  #pragma unroll
  for (int m = 0; m < 4; ++m)
    #pragma unroll
    for (int n = 0; n < 4; ++n) acc[m][n] = (f32x4){0.f,0.f,0.f,0.f};

  for (int k0 = 0; k0 < 512; k0 += 32) {
    #pragma unroll
    for (int i = 0; i < 4; ++i) {
      int q = tid + i*256;       // 0..1023
      int tt = q >> 5;           // 0..31
      int c4 = (q & 31) * 4;     // 0..124
      size_t row = ((size_t)b*T_ + t0 + k0 + tt) * 256;
      float4 av = *(const float4*)(Ab + row + c0 + c4);
      float4 bv = *(const float4*)(Bb + row + d0 + c4);
      split2(av.x, &Ah[c4+0][tt], &Al[c4+0][tt]);
      split2(av.y, &Ah[c4+1][tt], &Al[c4+1][tt]);
      split2(av.z, &Ah[c4+2][tt], &Al[c4+2][tt]);
      split2(av.w, &Ah[c4+3][tt], &Al[c4+3][tt]);
      split2(bv.x, &Bh[c4+0][tt], &Bl[c4+0][tt]);
      split2(bv.y, &Bh[c4+1][tt], &Bl[c4+1][tt]);
      split2(bv.z, &Bh[c4+2][tt], &Bl[c4+2][tt]);
      split2(bv.w, &Bh[c4+3][tt], &Bl[c4+3][tt]);
    }
    __syncthreads();
    half8 ah[4], al[4], bh[4], bl[4];
    #pragma unroll
    for (int m = 0; m < 4; ++m) {
      ah[m] = *(const half8*)&Ah[wr*64 + m*16 + lr][kg*8];
      al[m] = *(const half8*)&Al[wr*64 + m*16 + lr][kg*8];
    }
    #pragma unroll
    for (int n = 0; n < 4; ++n) {
      bh[n] = *(const half8*)&Bh[wc*64 + n*16 + lr][kg*8];
      bl[n] = *(const half8*)&Bl[wc*64 + n*16 + lr][kg*8];
    }
    #pragma unroll
    for (int m = 0; m < 4; ++m)
      #pragma unroll
      for (int n = 0; n < 4; ++n) {
        acc[m][n] = __builtin_amdgcn_mfma_f32_16x16x32_f16(ah[m], bh[n], acc[m][n], 0, 0, 0);
        acc[m][n] = __builtin_amdgcn_mfma_f32_16x16x32_f16(al[m], bh[n], acc[m][n], 0, 0, 0);
        acc[m][n] = __builtin_amdgcn_mfma_f32_16x16x32_f16(ah[m], bl[n], acc[m][n], 0, 0, 0);
      }
    __syncthreads();
  }
  float* dst = pg + ((size_t)(slab*B_ + b)*4 + quad)*16384;
  #pragma unroll
  for (int m = 0; m < 4; ++m)
    #pragma unroll
    for (int n = 0; n < 4; ++n) {
      int cl = wr*64 + m*16 + kg*4;
      int dl = wc*64 + n*16 + lr;
      #pragma unroll
      for (int r = 0; r < 4; ++r)
        dst[(size_t)(cl + r)*128 + dl] = acc[m][n][r];
    }
}

// reduce slabs + softmax(G/T) per row. grid (B*256), 64 threads.
__global__ __launch_bounds__(64) void gram_smax_k(
    const float* __restrict__ pg, float* __restrict__ G)
{
  int row = blockIdx.x;          // b*256 + c
  int b = row >> 8, c = row & 255;
  int l = threadIdx.x;
  int d4 = l * 4;
  int quad = ((c >= 128) ? 2 : 0) | ((d4 >= 128) ? 1 : 0);
  size_t base = ((size_t)b*4 + quad)*16384 + (size_t)(c & 127)*128 + (d4 & 127);
  float s0 = 0.f, s1 = 0.f, s2 = 0.f, s3 = 0.f;
  for (int sl = 0; sl < 16; ++sl) {
    const float* p = pg + (size_t)sl*(B_*4*16384) + base;
    float4 v = *(const float4*)p;
    s0 += v.x; s1 += v.y; s2 += v.z; s3 += v.w;
  }
  float v[4] = {s0*(1.f/T_), s1*(1.f/T_), s2*(1.f/T_), s3*(1.f/T_)};
  float mx = fmaxf(fmaxf(v[0], v[1]), fmaxf(v[2], v[3]));
  #pragma unroll
  for (int off = 32; off > 0; off >>= 1) mx = fmaxf(mx, __shfl_xor(mx, off));
  float s = 0.f;
  #pragma unroll
  for (int j = 0; j < 4; ++j) { v[j] = expf(v[j] - mx); s += v[j]; }
  #pragma unroll
  for (int off = 32; off > 0; off >>= 1) s += __shfl_xor(s, off);
  float inv = 1.f / s;
  float* dst = G + (size_t)b*65536 + (size_t)c*256 + d4;
  #pragma unroll
  for (int j = 0; j < 4; ++j) dst[j] = v[j] * inv;
}

// ============================================================================
// Final: out[b,o,t] = (sum_c fst[b,t,c]*Wn[o,c] + bn[o]) * mask[b,t]
// ============================================================================
__global__ __launch_bounds__(256) void final_k(
    const float* __restrict__ A, const float* __restrict__ Wn,
    const float* __restrict__ bn, const float* __restrict__ mask,
    float* __restrict__ out)
{
  int b = blockIdx.y, t0 = blockIdx.x * 32;
  __shared__ float As[32][257];
  int tid = threadIdx.x;
  #pragma unroll
  for (int i = 0; i < 8; ++i) {
    int f4 = tid + i*256;
    int rr = f4 >> 6;
    int c4 = (f4 & 63) * 4;
    float4 v = *(const float4*)(A + ((size_t)b*T_ + t0 + rr)*256 + c4);
    As[rr][c4]=v.x; As[rr][c4+1]=v.y; As[rr][c4+2]=v.z; As[rr][c4+3]=v.w;
  }
  __syncthreads();
  int t  = tid & 31;
  int og = tid >> 5;
  float m = mask[(size_t)b*T_ + t0 + t];
  for (int o = og*6; o < og*6 + 6; ++o) {
    float acc = bn[o];
    const float* wr = Wn + o*256;
    #pragma unroll 8
    for (int c = 0; c < 256; ++c) acc = fmaf(As[t][c], wr[c], acc);
    out[((size_t)b*48 + o)*T_ + t0 + t] = acc * m;
  }
}

// ============================================================================
extern "C" void kernel_launch(void* const* d_in, const int* in_sizes, int n_in,
                              void* d_out, int out_size, void* d_ws, size_t ws_size,
                              hipStream_t stream) {
  const float* x         = (const float*)d_in[0];
  const float* mask      = (const float*)d_in[1];
  const float* conv_in_w = (const float*)d_in[2];
  const float* conv_in_b = (const float*)d_in[3];
  const float* conv_t_w  = (const float*)d_in[4];
  const float* conv_t_b  = (const float*)d_in[5];
  const float* sfi_cs_w  = (const float*)d_in[6];
  const float* sfi_cs_b  = (const float*)d_in[7];
  const float* sfi_ff1_w = (const float*)d_in[8];
  const float* sfi_ff1_b = (const float*)d_in[9];
  const float* sfi_ff2_w = (const float*)d_in[10];
  const float* sfi_ff2_b = (const float*)d_in[11];
  const float* ff_w      = (const float*)d_in[12];
  const float* ff_b      = (const float*)d_in[13];
  const float* qw = (const float*)d_in[14]; const float* qb = (const float*)d_in[15];
  const float* kw = (const float*)d_in[16]; const float* kb = (const float*)d_in[17];
  const float* vw = (const float*)d_in[18]; const float* vb = (const float*)d_in[19];
  const float* ow = (const float*)d_in[20]; const float* ob = (const float*)d_in[21];
  const float* co_w = (const float*)d_in[22]; const float* co_b = (const float*)d_in[23];
  const float* out_w = (const float*)d_in[24]; const float* out_b = (const float*)d_in[25];

  float* ws = (float*)d_ws;
  const size_t BT = (size_t)B_ * T_;
  // ---- workspace layout (floats) ---- total ~44.4M floats = 178 MB (same as r3)
  float* small = ws;                        // BT*64 (xi5 / fs / cwt+pkv)
  float* fstA  = small + BT*64;             // BT*256
  float* fstB  = fstA + BT*256;
  float* Tb1   = fstB + BT*256;
  float* Tb2   = Tb1 + BT*256;
  float* Tb3   = Tb2 + BT*256;
  float* gram  = Tb3 + BT*256;              // B*256*256
  float* stats = gram + (size_t)B_*256*256; // B*512
  float* kvbuf = stats + B_*512;            // 16*4160
  float* cwt   = small;                     // 3*65536 = 196608 floats
  float* pkv   = small + 262144;            // 16*16*4160 = 1064960 floats

  dim3 gh(2, T_/128, B_);
  dim3 b256(256);

  init_k<<<dim3((unsigned)(BT*64/256)), b256, 0, stream>>>(x, conv_in_w, conv_in_b, small);
  gemm_h<0,0><<<gh, b256, 0, stream>>>(small, conv_t_w, conv_t_b, nullptr, fstA,
                                       64, 0, nullptr);

  float* fst  = fstA;
  float* fstN = fstB;
  int count = 0;
  for (int i = 0; i < 10; ++i) {
    if (i == 1 || i == 3 || i == 5 || i == 7) {
      // ---- SFI ----
      float* pgram = fstN;  // dead until ff2 writes it
      fs_k<<<dim3((unsigned)(BT*64/256)), b256, 0, stream>>>(x, conv_in_w, conv_in_b, small, count);
      gemm_h<0,0><<<gh, b256, 0, stream>>>(small, sfi_cs_w + (size_t)count*256*64,
                                           sfi_cs_b + count*256, nullptr, Tb1,
                                           64, 0, nullptr);
      gram_part_k<<<dim3(16, 4, B_), b256, 0, stream>>>(Tb1, fst, pgram);
      gram_smax_k<<<dim3(B_*256), dim3(64), 0, stream>>>(pgram, gram);
      gemm_h<0,0><<<gh, b256, 0, stream>>>(fst, gram, nullptr, fst, Tb2,
                                           256, (size_t)256*256, nullptr);
      gemm_h<3,0><<<gh, b256, 0, stream>>>(Tb2, sfi_ff1_w + (size_t)count*256*256,
                                           sfi_ff1_b + count*256, nullptr, Tb3,
                                           256, 0, nullptr);
      gemm_h<0,0><<<gh, b256, 0, stream>>>(Tb3, sfi_ff2_w + (size_t)count*256*256,
                                           sfi_ff2_b + count*256, fst, fstN,
                                           256, 0, nullptr);
      float* tmp = fst; fst = fstN; fstN = tmp;
      ++count;
    }
    // ---- attention module ----
    int dil = 1 << i;
    convw_prep_k<<<dim3(768), b256, 0, stream>>>(ff_w + (size_t)i*256*256*3, cwt);
    conv_h<<<gh, b256, 0, stream>>>(fst, cwt, ff_b + i*256, fstN, dil);
    hipMemsetAsync(stats, 0, (size_t)B_*512*sizeof(float), stream);
    stats_k<<<dim3(32, B_), b256, 0, stream>>>(fstN, stats);
    finstats_k<<<dim3(B_), b256, 0, stream>>>(stats);
    gemm_qkv_k<<<dim3(6, T_/128, B_), b256, 0, stream>>>(
        fstN, qw + (size_t)i*256*256, kw + (size_t)i*256*256, vw + (size_t)i*256*256,
        qb + i*256, kb + i*256, vb + i*256, Tb1, Tb2, Tb3, stats);
    kv_part_k<<<dim3(16, 16), b256, 0, stream>>>(Tb2, Tb3, pkv);
    kv_final_k<<<dim3(16), b256, 0, stream>>>(pkv, kvbuf);
    att_apply_k<<<dim3(T_/128, 16), b256, 0, stream>>>(Tb1, kvbuf, Tb1);   // in-place
    gemm_h<0,0><<<gh, b256, 0, stream>>>(Tb1, ow + (size_t)i*256*256, ob + i*256,
                                         fstN, Tb2, 256, 0, nullptr);
    gemm_h<0,0><<<gh, b256, 0, stream>>>(Tb2, co_w + (size_t)i*256*256, co_b + i*256,
                                         fst, fstN, 256, 0, nullptr);
    float* tmp = fst; fst = fstN; fstN = tmp;
  }
  final_k<<<dim3(T_/32, B_), b256, 0, stream>>>(fst, out_w, out_b, mask, (float*)d_out);
}

// Round 5
// 3763.641 us; speedup vs baseline: 2.7982x; 1.1382x over previous
//
#include <hip/hip_runtime.h>

#define T_ 8192
#define B_ 4

typedef _Float16 h16;
typedef _Float16 half4v __attribute__((ext_vector_type(4)));
typedef _Float16 half8 __attribute__((ext_vector_type(8)));
typedef float    f32x4 __attribute__((ext_vector_type(4)));

__device__ __forceinline__ void split2(float v, h16* hp, h16* lp) {
  h16 h = (h16)v; *hp = h; *lp = (h16)(v - (float)h);
}
__device__ __forceinline__ float join2(h16 h, h16 l) {
  return (float)h + (float)l;
}

// ============================================================================
// init/fs: channel c of input projection -> small planes (B,T,64)
// ============================================================================
__global__ __launch_bounds__(256) void init_fs_k(
    const float* __restrict__ x, const float* __restrict__ cw,
    const float* __restrict__ cb, h16* __restrict__ sh, h16* __restrict__ sl,
    int c)
{
  size_t idx = (size_t)blockIdx.x * 256 + threadIdx.x;   // over B*T*64
  int n = (int)(idx & 63);
  int t = (int)((idx >> 6) & (T_ - 1));
  int b = (int)(idx >> 19);
  float x0 = x[(((size_t)b*3 + 0)*T_ + t)*64 + n];
  float x1 = x[(((size_t)b*3 + 1)*T_ + t)*64 + n];
  float x2 = x[(((size_t)b*3 + 2)*T_ + t)*64 + n];
  float v = cb[c] + x0*cw[c*3] + x1*cw[c*3+1] + x2*cw[c*3+2];
  split2(v, &sh[idx], &sl[idx]);
}

// generic f32 -> hi/lo planes
__global__ __launch_bounds__(256) void wsplit_k(
    const float* __restrict__ src, h16* __restrict__ dh, h16* __restrict__ dl,
    int n)
{
  int i = blockIdx.x*256 + threadIdx.x;
  if (i < n) split2(src[i], &dh[i], &dl[i]);
}

// per-layer weight prep: conv [n][k][tap]->[tap][n][k] + 5 projection mats
__global__ __launch_bounds__(256) void wprep_k(
    const float* __restrict__ ffw, const float* __restrict__ qw,
    const float* __restrict__ kw, const float* __restrict__ vw,
    const float* __restrict__ ow, const float* __restrict__ cow,
    h16* __restrict__ dh, h16* __restrict__ dl)
{
  int i = blockIdx.x*256 + threadIdx.x;   // 0..524287
  float v;
  if (i < 196608) {
    int tap = i >> 16, nk = i & 65535;
    v = ffw[(size_t)nk*3 + tap];
  } else {
    int m = (i - 196608) >> 16, e = i & 65535;
    const float* s = m==0 ? qw : m==1 ? kw : m==2 ? vw : m==3 ? ow : cow;
    v = s[e];
  }
  split2(v, &dh[i], &dl[i]);
}

// per-SFI weight prep: ff1(65536) + ff2(65536) + cs(16384)
__global__ __launch_bounds__(256) void sprep_k(
    const float* __restrict__ f1, const float* __restrict__ f2,
    const float* __restrict__ cs, h16* __restrict__ dh, h16* __restrict__ dl)
{
  int i = blockIdx.x*256 + threadIdx.x;   // 0..147455
  float v = (i < 65536) ? f1[i] : (i < 131072) ? f2[i-65536] : cs[i-131072];
  split2(v, &dh[i], &dl[i]);
}

// ============================================================================
// Pre-split fp16x2 MFMA GEMM: C = act(A @ W^T + bias) (+resid), N=256 tile 128
// A planes (B,T,K); W planes (256,K) (+wbs per batch); out/resid planes.
// ============================================================================
template<int ACT>
__global__ __launch_bounds__(256, 2) void gemm_p(
    const h16* __restrict__ Agh, const h16* __restrict__ Agl,
    const h16* __restrict__ Wgh, const h16* __restrict__ Wgl,
    const float* __restrict__ bias,
    const h16* __restrict__ Rh, const h16* __restrict__ Rl,
    h16* __restrict__ Ch, h16* __restrict__ Cl,
    int K, size_t wbs)
{
  int b  = blockIdx.z;
  int n0 = blockIdx.x * 128;
  int t0 = blockIdx.y * 128;
  const h16* Ah_g = Agh + (size_t)b*T_*K;
  const h16* Al_g = Agl + (size_t)b*T_*K;
  const h16* Wh_g = Wgh + (size_t)b*wbs;
  const h16* Wl_g = Wgl + (size_t)b*wbs;
  __shared__ h16 Ah[128][40], Al[128][40], Wh[128][40], Wl[128][40];
  int tid = threadIdx.x, l = tid & 63, wid = tid >> 6;
  int wr = wid >> 1, wc = wid & 1, lr = l & 15, kg = l >> 4;
  f32x4 acc[4][4];
  #pragma unroll
  for (int m = 0; m < 4; ++m)
    #pragma unroll
    for (int n = 0; n < 4; ++n) acc[m][n] = (f32x4){0.f,0.f,0.f,0.f};

  for (int k0 = 0; k0 < K; k0 += 32) {
    #pragma unroll
    for (int i = 0; i < 2; ++i) {
      int q = tid + i*256;             // 0..511
      int row = q >> 2, kc = (q & 3) * 8;
      size_t aoff = (size_t)(t0 + row)*K + k0 + kc;
      size_t woff = (size_t)(n0 + row)*K + k0 + kc;
      *(half8*)&Ah[row][kc] = *(const half8*)(Ah_g + aoff);
      *(half8*)&Al[row][kc] = *(const half8*)(Al_g + aoff);
      *(half8*)&Wh[row][kc] = *(const half8*)(Wh_g + woff);
      *(half8*)&Wl[row][kc] = *(const half8*)(Wl_g + woff);
    }
    __syncthreads();
    half8 ah[4], al[4], wh[4], wl[4];
    #pragma unroll
    for (int m = 0; m < 4; ++m) {
      ah[m] = *(const half8*)&Ah[wr*64 + m*16 + lr][kg*8];
      al[m] = *(const half8*)&Al[wr*64 + m*16 + lr][kg*8];
    }
    #pragma unroll
    for (int n = 0; n < 4; ++n) {
      wh[n] = *(const half8*)&Wh[wc*64 + n*16 + lr][kg*8];
      wl[n] = *(const half8*)&Wl[wc*64 + n*16 + lr][kg*8];
    }
    #pragma unroll
    for (int m = 0; m < 4; ++m)
      #pragma unroll
      for (int n = 0; n < 4; ++n) {
        acc[m][n] = __builtin_amdgcn_mfma_f32_16x16x32_f16(ah[m], wh[n], acc[m][n], 0, 0, 0);
        acc[m][n] = __builtin_amdgcn_mfma_f32_16x16x32_f16(al[m], wh[n], acc[m][n], 0, 0, 0);
        acc[m][n] = __builtin_amdgcn_mfma_f32_16x16x32_f16(ah[m], wl[n], acc[m][n], 0, 0, 0);
      }
    __syncthreads();
  }
  #pragma unroll
  for (int m = 0; m < 4; ++m)
    #pragma unroll
    for (int n = 0; n < 4; ++n) {
      int col = n0 + wc*64 + n*16 + lr;
      float bi = bias ? bias[col] : 0.f;
      #pragma unroll
      for (int r = 0; r < 4; ++r) {
        int row = t0 + wr*64 + m*16 + kg*4 + r;
        size_t off = ((size_t)b*T_ + row)*256 + col;
        float v = acc[m][n][r] + bi;
        if (ACT == 1) v = fmaxf(v, 0.f);
        if (ACT == 2) v = 1.f/(1.f + expf(-v));
        if (ACT == 3) v = 0.5f*v*(1.f + erff(v*0.7071067811865475f));
        if (Rh) v += join2(Rh[off], Rl[off]);
        split2(v, &Ch[off], &Cl[off]);
      }
    }
}

// ============================================================================
// Dilated conv: 3-tap accumulated MFMA GEMM + fused instance-norm stats.
// W planes laid out [tap][256][256].
// ============================================================================
__global__ __launch_bounds__(256, 2) void conv_p(
    const h16* __restrict__ Agh, const h16* __restrict__ Agl,
    const h16* __restrict__ Wgh, const h16* __restrict__ Wgl,
    const float* __restrict__ bias,
    h16* __restrict__ Ch, h16* __restrict__ Cl,
    float* __restrict__ stats, int dil)
{
  int b  = blockIdx.z;
  int n0 = blockIdx.x * 128;
  int t0 = blockIdx.y * 128;
  const h16* Ah_g = Agh + (size_t)b*T_*256;
  const h16* Al_g = Agl + (size_t)b*T_*256;
  __shared__ h16 Ah[128][40], Al[128][40], Wh[128][40], Wl[128][40];
  __shared__ float cstat[2][128];
  int tid = threadIdx.x, l = tid & 63, wid = tid >> 6;
  int wr = wid >> 1, wc = wid & 1, lr = l & 15, kg = l >> 4;
  f32x4 acc[4][4];
  #pragma unroll
  for (int m = 0; m < 4; ++m)
    #pragma unroll
    for (int n = 0; n < 4; ++n) acc[m][n] = (f32x4){0.f,0.f,0.f,0.f};

  for (int tap = 0; tap < 3; ++tap) {
    int off = (tap - 1) * dil;
    for (int k0 = 0; k0 < 256; k0 += 32) {
      #pragma unroll
      for (int i = 0; i < 2; ++i) {
        int q = tid + i*256;
        int row = q >> 2, kc = (q & 3) * 8;
        int rt = t0 + row + off;
        half8 a8h = (half8)(h16)0.f, a8l = (half8)(h16)0.f;
        if ((unsigned)rt < (unsigned)T_) {
          size_t aoff = (size_t)rt*256 + k0 + kc;
          a8h = *(const half8*)(Ah_g + aoff);
          a8l = *(const half8*)(Al_g + aoff);
        }
        *(half8*)&Ah[row][kc] = a8h;
        *(half8*)&Al[row][kc] = a8l;
        size_t woff = (size_t)tap*65536 + (size_t)(n0 + row)*256 + k0 + kc;
        *(half8*)&Wh[row][kc] = *(const half8*)(Wgh + woff);
        *(half8*)&Wl[row][kc] = *(const half8*)(Wgl + woff);
      }
      __syncthreads();
      half8 ah[4], al[4], wh[4], wl[4];
      #pragma unroll
      for (int m = 0; m < 4; ++m) {
        ah[m] = *(const half8*)&Ah[wr*64 + m*16 + lr][kg*8];
        al[m] = *(const half8*)&Al[wr*64 + m*16 + lr][kg*8];
      }
      #pragma unroll
      for (int n = 0; n < 4; ++n) {
        wh[n] = *(const half8*)&Wh[wc*64 + n*16 + lr][kg*8];
        wl[n] = *(const half8*)&Wl[wc*64 + n*16 + lr][kg*8];
      }
      #pragma unroll
      for (int m = 0; m < 4; ++m)
        #pragma unroll
        for (int n = 0; n < 4; ++n) {
          acc[m][n] = __builtin_amdgcn_mfma_f32_16x16x32_f16(ah[m], wh[n], acc[m][n], 0, 0, 0);
          acc[m][n] = __builtin_amdgcn_mfma_f32_16x16x32_f16(al[m], wh[n], acc[m][n], 0, 0, 0);
          acc[m][n] = __builtin_amdgcn_mfma_f32_16x16x32_f16(ah[m], wl[n], acc[m][n], 0, 0, 0);
        }
      __syncthreads();
    }
  }
  cstat[tid >> 7][tid & 127] = 0.f;
  __syncthreads();
  #pragma unroll
  for (int n = 0; n < 4; ++n) {
    int cl = wc*64 + n*16 + lr;
    int col = n0 + cl;
    float bi = bias[col];
    float s = 0.f, s2 = 0.f;
    #pragma unroll
    for (int m = 0; m < 4; ++m)
      #pragma unroll
      for (int r = 0; r < 4; ++r) {
        int row = t0 + wr*64 + m*16 + kg*4 + r;
        size_t off = ((size_t)b*T_ + row)*256 + col;
        float v = fmaxf(acc[m][n][r] + bi, 0.f);
        split2(v, &Ch[off], &Cl[off]);
        s += v; s2 += v*v;
      }
    atomicAdd(&cstat[0][cl], s);
    atomicAdd(&cstat[1][cl], s2);
  }
  __syncthreads();
  int f = tid & 127;
  if (tid < 128) atomicAdd(&stats[b*512 + n0 + f],       cstat[0][f]);
  else           atomicAdd(&stats[b*512 + 256 + n0 + f], cstat[1][f]);
}

__global__ __launch_bounds__(256) void finstats_k(float* __restrict__ stats)
{
  int i = blockIdx.x * 256 + threadIdx.x;   // B*256
  int b = i >> 8, f = i & 255;
  float s  = stats[b*512 + f];
  float s2 = stats[b*512 + 256 + f];
  float m  = s * (1.f/T_);
  float v  = s2 * (1.f/T_) - m*m;
  stats[b*512 + f]       = m;
  stats[b*512 + 256 + f] = rsqrtf(fmaxf(v, 0.f) + 1e-5f);
}

// normalized A -> pre-split planes (one elementwise pass)
__global__ __launch_bounds__(256) void norm_split_k(
    const h16* __restrict__ Xh, const h16* __restrict__ Xl,
    const float* __restrict__ stats, h16* __restrict__ Qh, h16* __restrict__ Ql)
{
  size_t base = ((size_t)blockIdx.x*256 + threadIdx.x) * 8;  // over B*T*256
  int f0 = (int)(base & 255);
  int b  = (int)(base >> 21);
  const float* st = stats + b*512;
  half8 xh = *(const half8*)(Xh + base);
  half8 xl = *(const half8*)(Xl + base);
  half8 oh, ol;
  #pragma unroll
  for (int j = 0; j < 8; ++j) {
    float v = join2(xh[j], xl[j]);
    v = (v - st[f0+j]) * st[256 + f0+j];
    h16 hh = (h16)v;
    oh[j] = hh; ol[j] = (h16)(v - (float)hh);
  }
  *(half8*)(Qh + base) = oh;
  *(half8*)(Ql + base) = ol;
}

// ============================================================================
// kv partial: KV[d,e] & Ksum[d] over 512-t chunk, planes input. grid (16,16).
// ============================================================================
__global__ __launch_bounds__(256) void kv_part_p(
    const h16* __restrict__ Kh, const h16* __restrict__ Kl,
    const h16* __restrict__ Vh, const h16* __restrict__ Vl,
    float* __restrict__ pkv)
{
  int bh = blockIdx.y, b = bh >> 2, h = bh & 3;
  int t0 = blockIdx.x * 512;
  __shared__ float Ks[64][68];
  __shared__ float Vs[64][68];
  __shared__ float ksred[64];
  int tid = threadIdx.x;
  int wv = tid >> 6;
  int dq = (tid >> 2) & 15;
  int e4 = tid & 3, e0 = e4 * 16;
  float acc[4][16] = {};
  float ks4[4] = {};
  for (int w = 0; w < 8; ++w) {
    #pragma unroll
    for (int i = 0; i < 2; ++i) {
      int q = tid + i*256;       // 0..511
      int r = q >> 3;
      int c8 = (q & 7) * 8;
      size_t off = ((size_t)b*T_ + t0 + w*64 + r)*256 + h*64 + c8;
      half8 kh = *(const half8*)(Kh + off), kl = *(const half8*)(Kl + off);
      half8 vh = *(const half8*)(Vh + off), vl = *(const half8*)(Vl + off);
      float kf[8], vf[8];
      #pragma unroll
      for (int j = 0; j < 8; ++j) { kf[j] = join2(kh[j], kl[j]); vf[j] = join2(vh[j], vl[j]); }
      *(float4*)&Ks[r][c8]   = *(float4*)&kf[0];
      *(float4*)&Ks[r][c8+4] = *(float4*)&kf[4];
      *(float4*)&Vs[r][c8]   = *(float4*)&vf[0];
      *(float4*)&Vs[r][c8+4] = *(float4*)&vf[4];
    }
    __syncthreads();
    #pragma unroll 4
    for (int tt = wv*16; tt < wv*16 + 16; ++tt) {
      float4 k4 = *(const float4*)&Ks[tt][dq*4];
      if (e4 == 0) {
        ks4[0] += k4.x; ks4[1] += k4.y; ks4[2] += k4.z; ks4[3] += k4.w;
      }
      float va[16];
      *(float4*)&va[0]  = *(const float4*)&Vs[tt][e0+0];
      *(float4*)&va[4]  = *(const float4*)&Vs[tt][e0+4];
      *(float4*)&va[8]  = *(const float4*)&Vs[tt][e0+8];
      *(float4*)&va[12] = *(const float4*)&Vs[tt][e0+12];
      float ka[4] = {k4.x, k4.y, k4.z, k4.w};
      #pragma unroll
      for (int i = 0; i < 4; ++i)
        #pragma unroll
        for (int j = 0; j < 16; ++j)
          acc[i][j] = fmaf(ka[i], va[j], acc[i][j]);
    }
    __syncthreads();
  }
  for (int w = 0; w < 4; ++w) {
    if (wv == w) {
      #pragma unroll
      for (int i = 0; i < 4; ++i) {
        #pragma unroll
        for (int j = 0; j < 16; ++j) {
          if (w == 0) Ks[dq*4+i][e0+j] = acc[i][j];
          else        Ks[dq*4+i][e0+j] += acc[i][j];
        }
        if (e4 == 0) {
          if (w == 0) ksred[dq*4+i] = ks4[i];
          else        ksred[dq*4+i] += ks4[i];
        }
      }
    }
    __syncthreads();
  }
  float* dst = pkv + ((size_t)blockIdx.x*16 + bh)*4160;
  #pragma unroll
  for (int i = 0; i < 16; ++i) {
    int idx = tid + i*256;
    dst[idx] = Ks[idx >> 6][idx & 63];
  }
  if (tid < 64) dst[4096 + tid] = ksred[tid];
}

__global__ __launch_bounds__(256) void kv_final_k(
    const float* __restrict__ pkv, float* __restrict__ kv)
{
  int bh = blockIdx.x;
  for (int idx = threadIdx.x; idx < 4160; idx += 256) {
    float s = 0.f;
    #pragma unroll
    for (int c = 0; c < 16; ++c) s += pkv[((size_t)c*16 + bh)*4160 + idx];
    kv[(size_t)bh*4160 + idx] = s;
  }
}

// ============================================================================
// att apply from planes; O may alias Q (block consumes its tile first).
// ============================================================================
__global__ __launch_bounds__(256) void att_apply_p(
    const h16* __restrict__ Qh, const h16* __restrict__ Ql,
    const float* __restrict__ kv,
    h16* __restrict__ Oh, h16* __restrict__ Ol)
{
  int bh = blockIdx.y, b = bh >> 2, h = bh & 3;
  int t0 = blockIdx.x * 128;
  __shared__ float QsT[64][132];
  __shared__ float KVs[64][68];
  __shared__ float ks[64];
  int tid = threadIdx.x;
  const float* src = kv + (size_t)bh*4160;
  #pragma unroll
  for (int i = 0; i < 16; ++i) {
    int idx = tid + i*256;
    KVs[idx >> 6][idx & 63] = src[idx];
  }
  if (tid < 64) ks[tid] = src[4096 + tid] + 1e-6f;
  #pragma unroll
  for (int i = 0; i < 4; ++i) {
    int q8 = tid + i*256;      // 0..1023
    int t  = q8 >> 3;          // 0..127
    int d8 = (q8 & 7) * 8;
    size_t off = ((size_t)b*T_ + t0 + t)*256 + h*64 + d8;
    half8 qh = *(const half8*)(Qh + off), ql = *(const half8*)(Ql + off);
    #pragma unroll
    for (int j = 0; j < 8; ++j) QsT[d8+j][t] = join2(qh[j], ql[j]);
  }
  __syncthreads();
  int t2 = (tid >> 2) * 2;
  int e0 = (tid & 3) * 16;
  float acc[2][16] = {};
  float den[2] = {};
  for (int dd = 0; dd < 64; ++dd) {
    float2 q = *(const float2*)&QsT[dd][t2];
    float kd = ks[dd];
    den[0] = fmaf(q.x, kd, den[0]);
    den[1] = fmaf(q.y, kd, den[1]);
    float va[16];
    *(float4*)&va[0]  = *(const float4*)&KVs[dd][e0+0];
    *(float4*)&va[4]  = *(const float4*)&KVs[dd][e0+4];
    *(float4*)&va[8]  = *(const float4*)&KVs[dd][e0+8];
    *(float4*)&va[12] = *(const float4*)&KVs[dd][e0+12];
    #pragma unroll
    for (int j = 0; j < 16; ++j) {
      acc[0][j] = fmaf(q.x, va[j], acc[0][j]);
      acc[1][j] = fmaf(q.y, va[j], acc[1][j]);
    }
  }
  #pragma unroll
  for (int ti = 0; ti < 2; ++ti) {
    float z = 1.f / den[ti];
    size_t off = ((size_t)b*T_ + t0 + t2 + ti)*256 + h*64 + e0;
    half8 vh, vl;
    #pragma unroll
    for (int j = 0; j < 8; ++j) {
      float v = acc[ti][j] * z;
      h16 hh = (h16)v; vh[j] = hh; vl[j] = (h16)(v - (float)hh);
    }
    *(half8*)(Oh + off) = vh;
    *(half8*)(Ol + off) = vl;
    #pragma unroll
    for (int j = 0; j < 8; ++j) {
      float v = acc[ti][j+8] * z;
      h16 hh = (h16)v; vh[j] = hh; vl[j] = (h16)(v - (float)hh);
    }
    *(half8*)(Oh + off + 8) = vh;
    *(half8*)(Ol + off + 8) = vl;
  }
}

// ============================================================================
// SFI gram partial (MFMA, transposed staging from planes). grid (16,4,B).
// ============================================================================
__global__ __launch_bounds__(256, 2) void gram_part_p(
    const h16* __restrict__ Agh, const h16* __restrict__ Agl,
    const h16* __restrict__ Bgh, const h16* __restrict__ Bgl,
    float* __restrict__ pg)
{
  int b = blockIdx.z;
  int quad = blockIdx.y;
  int slab = blockIdx.x;
  int c0 = (quad >> 1) * 128, d0 = (quad & 1) * 128;
  int t0 = slab * 512;
  __shared__ h16 Ah[128][40], Al[128][40], Bh[128][40], Bl[128][40];
  int tid = threadIdx.x, l = tid & 63, wid = tid >> 6;
  int wr = wid >> 1, wc = wid & 1, lr = l & 15, kg = l >> 4;
  f32x4 acc[4][4];
  #pragma unroll
  for (int m = 0; m < 4; ++m)
    #pragma unroll
    for (int n = 0; n < 4; ++n) acc[m][n] = (f32x4){0.f,0.f,0.f,0.f};

  for (int k0 = 0; k0 < 512; k0 += 32) {
    #pragma unroll
    for (int i = 0; i < 2; ++i) {
      int q = tid + i*256;       // 0..511
      int tt = q >> 4;           // 0..31
      int c8 = (q & 15) * 8;     // 0..120
      size_t row = ((size_t)b*T_ + t0 + k0 + tt) * 256;
      half8 a8h = *(const half8*)(Agh + row + c0 + c8);
      half8 a8l = *(const half8*)(Agl + row + c0 + c8);
      half8 b8h = *(const half8*)(Bgh + row + d0 + c8);
      half8 b8l = *(const half8*)(Bgl + row + d0 + c8);
      #pragma unroll
      for (int j = 0; j < 8; ++j) {
        Ah[c8+j][tt] = a8h[j]; Al[c8+j][tt] = a8l[j];
        Bh[c8+j][tt] = b8h[j]; Bl[c8+j][tt] = b8l[j];
      }
    }
    __syncthreads();
    half8 ah[4], al[4], bh4[4], bl4[4];
    #pragma unroll
    for (int m = 0; m < 4; ++m) {
      ah[m] = *(const half8*)&Ah[wr*64 + m*16 + lr][kg*8];
      al[m] = *(const half8*)&Al[wr*64 + m*16 + lr][kg*8];
    }
    #pragma unroll
    for (int n = 0; n < 4; ++n) {
      bh4[n] = *(const half8*)&Bh[wc*64 + n*16 + lr][kg*8];
      bl4[n] = *(const half8*)&Bl[wc*64 + n*16 + lr][kg*8];
    }
    #pragma unroll
    for (int m = 0; m < 4; ++m)
      #pragma unroll
      for (int n = 0; n < 4; ++n) {
        acc[m][n] = __builtin_amdgcn_mfma_f32_16x16x32_f16(ah[m], bh4[n], acc[m][n], 0, 0, 0);
        acc[m][n] = __builtin_amdgcn_mfma_f32_16x16x32_f16(al[m], bh4[n], acc[m][n], 0, 0, 0);
        acc[m][n] = __builtin_amdgcn_mfma_f32_16x16x32_f16(ah[m], bl4[n], acc[m][n], 0, 0, 0);
      }
    __syncthreads();
  }
  float* dst = pg + ((size_t)(slab*B_ + b)*4 + quad)*16384;
  #pragma unroll
  for (int m = 0; m < 4; ++m)
    #pragma unroll
    for (int n = 0; n < 4; ++n) {
      int cl = wr*64 + m*16 + kg*4;
      int dl = wc*64 + n*16 + lr;
      #pragma unroll
      for (int r = 0; r < 4; ++r)
        dst[(size_t)(cl + r)*128 + dl] = acc[m][n][r];
    }
}

// reduce slabs + softmax(G/T) per row -> G planes. grid (B*256), 64 threads.
__global__ __launch_bounds__(64) void gram_smax_p(
    const float* __restrict__ pg, h16* __restrict__ Gh, h16* __restrict__ Gl)
{
  int row = blockIdx.x;          // b*256 + c
  int b = row >> 8, c = row & 255;
  int l = threadIdx.x;
  int d4 = l * 4;
  int quad = ((c >= 128) ? 2 : 0) | ((d4 >= 128) ? 1 : 0);
  size_t base = ((size_t)b*4 + quad)*16384 + (size_t)(c & 127)*128 + (d4 & 127);
  float s0 = 0.f, s1 = 0.f, s2 = 0.f, s3 = 0.f;
  for (int sl = 0; sl < 16; ++sl) {
    const float* p = pg + (size_t)sl*(B_*4*16384) + base;
    float4 v = *(const float4*)p;
    s0 += v.x; s1 += v.y; s2 += v.z; s3 += v.w;
  }
  float v[4] = {s0*(1.f/T_), s1*(1.f/T_), s2*(1.f/T_), s3*(1.f/T_)};
  float mx = fmaxf(fmaxf(v[0], v[1]), fmaxf(v[2], v[3]));
  #pragma unroll
  for (int off = 32; off > 0; off >>= 1) mx = fmaxf(mx, __shfl_xor(mx, off));
  float s = 0.f;
  #pragma unroll
  for (int j = 0; j < 4; ++j) { v[j] = expf(v[j] - mx); s += v[j]; }
  #pragma unroll
  for (int off = 32; off > 0; off >>= 1) s += __shfl_xor(s, off);
  float inv = 1.f / s;
  size_t doff = (size_t)b*65536 + (size_t)c*256 + d4;
  half4v oh, ol;
  #pragma unroll
  for (int j = 0; j < 4; ++j) {
    float w = v[j] * inv;
    h16 hh = (h16)w; oh[j] = hh; ol[j] = (h16)(w - (float)hh);
  }
  *(half4v*)(Gh + doff) = oh;
  *(half4v*)(Gl + doff) = ol;
}

// ============================================================================
// Final: out[b,o,t] = (fst[b,t,:] . Wn[o,:] + bn[o]) * mask[b,t]
// ============================================================================
__global__ __launch_bounds__(256) void final_p(
    const h16* __restrict__ Ahp, const h16* __restrict__ Alp,
    const float* __restrict__ Wn, const float* __restrict__ bn,
    const float* __restrict__ mask, float* __restrict__ out)
{
  int b = blockIdx.y, t0 = blockIdx.x * 32;
  __shared__ float As[32][257];
  int tid = threadIdx.x;
  #pragma unroll
  for (int i = 0; i < 4; ++i) {
    int q8 = tid + i*256;          // 0..1023
    int rr = q8 >> 5;
    int c8 = (q8 & 31) * 8;
    size_t off = ((size_t)b*T_ + t0 + rr)*256 + c8;
    half8 vh = *(const half8*)(Ahp + off), vl = *(const half8*)(Alp + off);
    float f[8];
    #pragma unroll
    for (int j = 0; j < 8; ++j) f[j] = join2(vh[j], vl[j]);
    *(float4*)&As[rr][c8]   = *(float4*)&f[0];
    *(float4*)&As[rr][c8+4] = *(float4*)&f[4];
  }
  __syncthreads();
  int t  = tid & 31;
  int og = tid >> 5;
  float m = mask[(size_t)b*T_ + t0 + t];
  for (int o = og*6; o < og*6 + 6; ++o) {
    float acc = bn[o];
    const float* wr = Wn + o*256;
    #pragma unroll 8
    for (int c = 0; c < 256; ++c) acc = fmaf(As[t][c], wr[c], acc);
    out[((size_t)b*48 + o)*T_ + t0 + t] = acc * m;
  }
}

// ============================================================================
extern "C" void kernel_launch(void* const* d_in, const int* in_sizes, int n_in,
                              void* d_out, int out_size, void* d_ws, size_t ws_size,
                              hipStream_t stream) {
  const float* x         = (const float*)d_in[0];
  const float* mask      = (const float*)d_in[1];
  const float* conv_in_w = (const float*)d_in[2];
  const float* conv_in_b = (const float*)d_in[3];
  const float* conv_t_w  = (const float*)d_in[4];
  const float* conv_t_b  = (const float*)d_in[5];
  const float* sfi_cs_w  = (const float*)d_in[6];
  const float* sfi_cs_b  = (const float*)d_in[7];
  const float* sfi_ff1_w = (const float*)d_in[8];
  const float* sfi_ff1_b = (const float*)d_in[9];
  const float* sfi_ff2_w = (const float*)d_in[10];
  const float* sfi_ff2_b = (const float*)d_in[11];
  const float* ff_w      = (const float*)d_in[12];
  const float* ff_b      = (const float*)d_in[13];
  const float* qw = (const float*)d_in[14]; const float* qb = (const float*)d_in[15];
  const float* kw = (const float*)d_in[16]; const float* kb = (const float*)d_in[17];
  const float* vw = (const float*)d_in[18]; const float* vb = (const float*)d_in[19];
  const float* ow = (const float*)d_in[20]; const float* ob = (const float*)d_in[21];
  const float* co_w = (const float*)d_in[22]; const float* co_b = (const float*)d_in[23];
  const float* out_w = (const float*)d_in[24]; const float* out_b = (const float*)d_in[25];

  float* ws = (float*)d_ws;
  const size_t BT = (size_t)B_ * T_;
  const size_t NB = BT * 256;               // elements per big buffer
  // ---- regions (f32 units), total ~44.5M floats = 178 MB ----
  float* smallR = ws;                        // BT*64  (fs planes / pkv / wlay)
  float* bigR   = smallR + BT*64;            // 5 * NB
  float* GR     = bigR + 5*NB;               // B*65536
  float* statsR = GR + (size_t)B_*65536;     // B*512
  float* kvR    = statsR + (size_t)B_*512;   // 16*4160
  float* wsfiR  = kvR + 16*4160;             // 147456

  h16* small_h = (h16*)smallR; h16* small_l = small_h + BT*64;
  h16 *bigH[5], *bigL[5];
  for (int i = 0; i < 5; ++i) { bigH[i] = (h16*)(bigR + (size_t)i*NB); bigL[i] = bigH[i] + NB; }
  h16* G_h = (h16*)GR; h16* G_l = G_h + (size_t)B_*65536;
  float* stats = statsR;
  float* kvbuf = kvR;
  h16* wsfi_h = (h16*)wsfiR; h16* wsfi_l = wsfi_h + 147456;
  // aliased into small (dead between SFI fs usage): pkv + per-layer weights
  float* pkv   = smallR;                              // 16*16*4160 = 1064960 f32
  h16* wlay_h  = (h16*)(smallR + 1064960);            // 8*65536 elements
  h16* wlay_l  = wlay_h + 8*65536;

  dim3 gh(2, T_/128, B_);
  dim3 b256(256);

  // xi5 -> small planes; conv_t split -> wsfi[0..16384)
  init_fs_k<<<dim3((unsigned)(BT*64/256)), b256, 0, stream>>>(x, conv_in_w, conv_in_b, small_h, small_l, 4);
  wsplit_k<<<dim3(64), b256, 0, stream>>>(conv_t_w, wsfi_h, wsfi_l, 16384);
  gemm_p<0><<<gh, b256, 0, stream>>>(small_h, small_l, wsfi_h, wsfi_l, conv_t_b,
                                     nullptr, nullptr, bigH[0], bigL[0], 64, 0);

  int fi = 0, fo = 1;   // fst = big[fi], fstN = big[fo]
  int count = 0;
  for (int i = 0; i < 10; ++i) {
    if (i == 1 || i == 3 || i == 5 || i == 7) {
      // ---- SFI ----
      sprep_k<<<dim3(576), b256, 0, stream>>>(sfi_ff1_w + (size_t)count*65536,
                                              sfi_ff2_w + (size_t)count*65536,
                                              sfi_cs_w + (size_t)count*16384,
                                              wsfi_h, wsfi_l);
      init_fs_k<<<dim3((unsigned)(BT*64/256)), b256, 0, stream>>>(x, conv_in_w, conv_in_b, small_h, small_l, count);
      gemm_p<0><<<gh, b256, 0, stream>>>(small_h, small_l, wsfi_h + 131072, wsfi_l + 131072,
                                         sfi_cs_b + count*256, nullptr, nullptr,
                                         bigH[2], bigL[2], 64, 0);
      float* pgram = bigR + (size_t)fo*NB;  // dead f32 region
      gram_part_p<<<dim3(16, 4, B_), b256, 0, stream>>>(bigH[2], bigL[2], bigH[fi], bigL[fi], pgram);
      gram_smax_p<<<dim3(B_*256), dim3(64), 0, stream>>>(pgram, G_h, G_l);
      gemm_p<0><<<gh, b256, 0, stream>>>(bigH[fi], bigL[fi], G_h, G_l, nullptr,
                                         bigH[fi], bigL[fi], bigH[3], bigL[3], 256, 65536);
      gemm_p<3><<<gh, b256, 0, stream>>>(bigH[3], bigL[3], wsfi_h, wsfi_l,
                                         sfi_ff1_b + count*256, nullptr, nullptr,
                                         bigH[4], bigL[4], 256, 0);
      gemm_p<0><<<gh, b256, 0, stream>>>(bigH[4], bigL[4], wsfi_h + 65536, wsfi_l + 65536,
                                         sfi_ff2_b + count*256, bigH[fi], bigL[fi],
                                         bigH[fo], bigL[fo], 256, 0);
      int t = fi; fi = fo; fo = t;
      ++count;
    }
    // ---- attention module ----
    int dil = 1 << i;
    wprep_k<<<dim3(2048), b256, 0, stream>>>(ff_w + (size_t)i*196608,
                                             qw + (size_t)i*65536, kw + (size_t)i*65536,
                                             vw + (size_t)i*65536, ow + (size_t)i*65536,
                                             co_w + (size_t)i*65536, wlay_h, wlay_l);
    hipMemsetAsync(stats, 0, (size_t)B_*512*sizeof(float), stream);
    conv_p<<<gh, b256, 0, stream>>>(bigH[fi], bigL[fi], wlay_h, wlay_l, ff_b + i*256,
                                    bigH[fo], bigL[fo], stats, dil);
    finstats_k<<<dim3(B_), b256, 0, stream>>>(stats);
    norm_split_k<<<dim3((unsigned)(NB/2048)), b256, 0, stream>>>(bigH[fo], bigL[fo], stats,
                                                                 bigH[2], bigL[2]);
    // K (sigmoid) -> big3, V -> big4
    gemm_p<2><<<gh, b256, 0, stream>>>(bigH[2], bigL[2], wlay_h + 262144, wlay_l + 262144,
                                       kb + i*256, nullptr, nullptr, bigH[3], bigL[3], 256, 0);
    gemm_p<0><<<gh, b256, 0, stream>>>(bigH[2], bigL[2], wlay_h + 327680, wlay_l + 327680,
                                       vb + i*256, nullptr, nullptr, bigH[4], bigL[4], 256, 0);
    kv_part_p<<<dim3(16, 16), b256, 0, stream>>>(bigH[3], bigL[3], bigH[4], bigL[4], pkv);
    kv_final_k<<<dim3(16), b256, 0, stream>>>(pkv, kvbuf);
    // Q (sigmoid) -> big3 (K dead after kv_part)
    gemm_p<2><<<gh, b256, 0, stream>>>(bigH[2], bigL[2], wlay_h + 196608, wlay_l + 196608,
                                       qb + i*256, nullptr, nullptr, bigH[3], bigL[3], 256, 0);
    att_apply_p<<<dim3(T_/128, 16), b256, 0, stream>>>(bigH[3], bigL[3], kvbuf, bigH[3], bigL[3]);
    // o-proj + conv resid -> big4 ; co-proj + fst resid -> fstN
    gemm_p<0><<<gh, b256, 0, stream>>>(bigH[3], bigL[3], wlay_h + 393216, wlay_l + 393216,
                                       ob + i*256, bigH[fo], bigL[fo], bigH[4], bigL[4], 256, 0);
    gemm_p<0><<<gh, b256, 0, stream>>>(bigH[4], bigL[4], wlay_h + 458752, wlay_l + 458752,
                                       co_b + i*256, bigH[fi], bigL[fi], bigH[fo], bigL[fo], 256, 0);
    int t = fi; fi = fo; fo = t;
  }
  final_p<<<dim3(T_/32, B_), b256, 0, stream>>>(bigH[fi], bigL[fi], out_w, out_b, mask, (float*)d_out);
}

// Round 6
// 3479.552 us; speedup vs baseline: 3.0267x; 1.0816x over previous
//
#include <hip/hip_runtime.h>

#define T_ 8192
#define B_ 4

typedef _Float16 h16;
typedef _Float16 half4v __attribute__((ext_vector_type(4)));
typedef _Float16 half8 __attribute__((ext_vector_type(8)));
typedef float    f32x4 __attribute__((ext_vector_type(4)));

__device__ __forceinline__ void split2(float v, h16* hp, h16* lp) {
  h16 h = (h16)v; *hp = h; *lp = (h16)(v - (float)h);
}
__device__ __forceinline__ float join2(h16 h, h16 l) {
  return (float)h + (float)l;
}
// async 16B global -> LDS (dest is wave-uniform base + lane*16, linear)
__device__ __forceinline__ void gl2lds16(const void* g, void* l) {
  __builtin_amdgcn_global_load_lds(
      (const __attribute__((address_space(1))) unsigned int*)g,
      (__attribute__((address_space(3))) unsigned int*)l, 16, 0, 0);
}

// ============================================================================
// init/fs: channel c of input projection -> small planes (B,T,64)
// ============================================================================
__global__ __launch_bounds__(256) void init_fs_k(
    const float* __restrict__ x, const float* __restrict__ cw,
    const float* __restrict__ cb, h16* __restrict__ sh, h16* __restrict__ sl,
    int c)
{
  size_t idx = (size_t)blockIdx.x * 256 + threadIdx.x;   // over B*T*64
  int n = (int)(idx & 63);
  int t = (int)((idx >> 6) & (T_ - 1));
  int b = (int)(idx >> 19);
  float x0 = x[(((size_t)b*3 + 0)*T_ + t)*64 + n];
  float x1 = x[(((size_t)b*3 + 1)*T_ + t)*64 + n];
  float x2 = x[(((size_t)b*3 + 2)*T_ + t)*64 + n];
  float v = cb[c] + x0*cw[c*3] + x1*cw[c*3+1] + x2*cw[c*3+2];
  split2(v, &sh[idx], &sl[idx]);
}

// generic f32 -> hi/lo planes
__global__ __launch_bounds__(256) void wsplit_k(
    const float* __restrict__ src, h16* __restrict__ dh, h16* __restrict__ dl,
    int n)
{
  int i = blockIdx.x*256 + threadIdx.x;
  if (i < n) split2(src[i], &dh[i], &dl[i]);
}

// per-layer weight prep: conv [n][k][tap]->[tap][n][k] + 5 projection mats
__global__ __launch_bounds__(256) void wprep_k(
    const float* __restrict__ ffw, const float* __restrict__ qw,
    const float* __restrict__ kw, const float* __restrict__ vw,
    const float* __restrict__ ow, const float* __restrict__ cow,
    h16* __restrict__ dh, h16* __restrict__ dl)
{
  int i = blockIdx.x*256 + threadIdx.x;   // 0..524287
  float v;
  if (i < 196608) {
    int tap = i >> 16, nk = i & 65535;
    v = ffw[(size_t)nk*3 + tap];
  } else {
    int m = (i - 196608) >> 16, e = i & 65535;
    const float* s = m==0 ? qw : m==1 ? kw : m==2 ? vw : m==3 ? ow : cow;
    v = s[e];
  }
  split2(v, &dh[i], &dl[i]);
}

// per-SFI weight prep: ff1(65536) + ff2(65536) + cs(16384)
__global__ __launch_bounds__(256) void sprep_k(
    const float* __restrict__ f1, const float* __restrict__ f2,
    const float* __restrict__ cs, h16* __restrict__ dh, h16* __restrict__ dl)
{
  int i = blockIdx.x*256 + threadIdx.x;   // 0..147455
  float v = (i < 65536) ? f1[i] : (i < 131072) ? f2[i-65536] : cs[i-131072];
  split2(v, &dh[i], &dl[i]);
}

// ============================================================================
// Pre-split fp16x2 MFMA GEMM with global_load_lds staging.
// LDS: linear S[4][128][32] h16 (Ah,Al,Wh,Wl); 16B chunk (r,kc) holds global
// chunk kc ^ ((r>>1)&3) -> b128 reads land uniform across banks.
// ============================================================================
template<int ACT>
__global__ __launch_bounds__(256, 2) void gemm_p(
    const h16* __restrict__ Agh, const h16* __restrict__ Agl,
    const h16* __restrict__ Wgh, const h16* __restrict__ Wgl,
    const float* __restrict__ bias,
    const h16* __restrict__ Rh, const h16* __restrict__ Rl,
    h16* __restrict__ Ch, h16* __restrict__ Cl,
    int K, size_t wbs)
{
  int b  = blockIdx.z;
  int n0 = blockIdx.x * 128;
  int t0 = blockIdx.y * 128;
  const h16* Ah_g = Agh + (size_t)b*T_*K;
  const h16* Al_g = Agl + (size_t)b*T_*K;
  const h16* Wh_g = Wgh + (size_t)b*wbs;
  const h16* Wl_g = Wgl + (size_t)b*wbs;
  __shared__ h16 S[4][128][32];
  int tid = threadIdx.x, l = tid & 63, wid = tid >> 6;
  int wr = wid >> 1, wc = wid & 1, lr = l & 15, kg = l >> 4;
  f32x4 acc[4][4];
  #pragma unroll
  for (int m = 0; m < 4; ++m)
    #pragma unroll
    for (int n = 0; n < 4; ++n) acc[m][n] = (f32x4){0.f,0.f,0.f,0.f};

  for (int k0 = 0; k0 < K; k0 += 32) {
    #pragma unroll
    for (int i = 0; i < 8; ++i) {
      int c = i*256 + tid;                 // 0..2047 chunks
      int p = c >> 9, r = (c >> 2) & 127, kc = c & 3;
      int ks = k0 + ((kc ^ ((r >> 1) & 3)) << 3);
      const h16* src = (p == 0) ? Ah_g + (size_t)(t0 + r)*K + ks
                     : (p == 1) ? Al_g + (size_t)(t0 + r)*K + ks
                     : (p == 2) ? Wh_g + (size_t)(n0 + r)*K + ks
                                : Wl_g + (size_t)(n0 + r)*K + ks;
      gl2lds16(src, (h16*)S + (size_t)c*8);
    }
    __syncthreads();
    half8 ah[4], al[4], wh[4], wl[4];
    #pragma unroll
    for (int m = 0; m < 4; ++m) {
      int row = wr*64 + m*16 + lr;
      int ko = (kg ^ ((row >> 1) & 3)) * 8;
      ah[m] = *(const half8*)&S[0][row][ko];
      al[m] = *(const half8*)&S[1][row][ko];
    }
    #pragma unroll
    for (int n = 0; n < 4; ++n) {
      int row = wc*64 + n*16 + lr;
      int ko = (kg ^ ((row >> 1) & 3)) * 8;
      wh[n] = *(const half8*)&S[2][row][ko];
      wl[n] = *(const half8*)&S[3][row][ko];
    }
    #pragma unroll
    for (int m = 0; m < 4; ++m)
      #pragma unroll
      for (int n = 0; n < 4; ++n) {
        acc[m][n] = __builtin_amdgcn_mfma_f32_16x16x32_f16(ah[m], wh[n], acc[m][n], 0, 0, 0);
        acc[m][n] = __builtin_amdgcn_mfma_f32_16x16x32_f16(al[m], wh[n], acc[m][n], 0, 0, 0);
        acc[m][n] = __builtin_amdgcn_mfma_f32_16x16x32_f16(ah[m], wl[n], acc[m][n], 0, 0, 0);
      }
    __syncthreads();
  }
  #pragma unroll
  for (int m = 0; m < 4; ++m)
    #pragma unroll
    for (int n = 0; n < 4; ++n) {
      int col = n0 + wc*64 + n*16 + lr;
      float bi = bias ? bias[col] : 0.f;
      #pragma unroll
      for (int r = 0; r < 4; ++r) {
        int row = t0 + wr*64 + m*16 + kg*4 + r;
        size_t off = ((size_t)b*T_ + row)*256 + col;
        float v = acc[m][n][r] + bi;
        if (ACT == 1) v = fmaxf(v, 0.f);
        if (ACT == 2) v = 1.f/(1.f + expf(-v));
        if (ACT == 3) v = 0.5f*v*(1.f + erff(v*0.7071067811865475f));
        if (Rh) v += join2(Rh[off], Rl[off]);
        split2(v, &Ch[off], &Cl[off]);
      }
    }
}

// ============================================================================
// Dilated conv: 3-tap accumulated MFMA GEMM + fused instance-norm stats.
// global_load_lds staging; OOB rows redirect source to zbuf (16 zeroed bytes).
// W planes [tap][256][256].
// ============================================================================
__global__ __launch_bounds__(256, 2) void conv_p(
    const h16* __restrict__ Agh, const h16* __restrict__ Agl,
    const h16* __restrict__ Wgh, const h16* __restrict__ Wgl,
    const float* __restrict__ bias,
    h16* __restrict__ Ch, h16* __restrict__ Cl,
    float* __restrict__ stats, const float* __restrict__ zbuf, int dil)
{
  int b  = blockIdx.z;
  int n0 = blockIdx.x * 128;
  int t0 = blockIdx.y * 128;
  const h16* Ah_g = Agh + (size_t)b*T_*256;
  const h16* Al_g = Agl + (size_t)b*T_*256;
  __shared__ h16 S[4][128][32];
  __shared__ float cstat[2][128];
  int tid = threadIdx.x, l = tid & 63, wid = tid >> 6;
  int wr = wid >> 1, wc = wid & 1, lr = l & 15, kg = l >> 4;
  f32x4 acc[4][4];
  #pragma unroll
  for (int m = 0; m < 4; ++m)
    #pragma unroll
    for (int n = 0; n < 4; ++n) acc[m][n] = (f32x4){0.f,0.f,0.f,0.f};

  for (int tap = 0; tap < 3; ++tap) {
    int off = (tap - 1) * dil;
    const h16* Wh_t = Wgh + (size_t)tap*65536;
    const h16* Wl_t = Wgl + (size_t)tap*65536;
    for (int k0 = 0; k0 < 256; k0 += 32) {
      #pragma unroll
      for (int i = 0; i < 8; ++i) {
        int c = i*256 + tid;
        int p = c >> 9, r = (c >> 2) & 127, kc = c & 3;
        int ks = k0 + ((kc ^ ((r >> 1) & 3)) << 3);
        const h16* src;
        if (p < 2) {
          int rt = t0 + r + off;
          if ((unsigned)rt < (unsigned)T_)
            src = (p == 0 ? Ah_g : Al_g) + (size_t)rt*256 + ks;
          else
            src = (const h16*)zbuf;
        } else {
          src = (p == 2 ? Wh_t : Wl_t) + (size_t)(n0 + r)*256 + ks;
        }
        gl2lds16(src, (h16*)S + (size_t)c*8);
      }
      __syncthreads();
      half8 ah[4], al[4], wh[4], wl[4];
      #pragma unroll
      for (int m = 0; m < 4; ++m) {
        int row = wr*64 + m*16 + lr;
        int ko = (kg ^ ((row >> 1) & 3)) * 8;
        ah[m] = *(const half8*)&S[0][row][ko];
        al[m] = *(const half8*)&S[1][row][ko];
      }
      #pragma unroll
      for (int n = 0; n < 4; ++n) {
        int row = wc*64 + n*16 + lr;
        int ko = (kg ^ ((row >> 1) & 3)) * 8;
        wh[n] = *(const half8*)&S[2][row][ko];
        wl[n] = *(const half8*)&S[3][row][ko];
      }
      #pragma unroll
      for (int m = 0; m < 4; ++m)
        #pragma unroll
        for (int n = 0; n < 4; ++n) {
          acc[m][n] = __builtin_amdgcn_mfma_f32_16x16x32_f16(ah[m], wh[n], acc[m][n], 0, 0, 0);
          acc[m][n] = __builtin_amdgcn_mfma_f32_16x16x32_f16(al[m], wh[n], acc[m][n], 0, 0, 0);
          acc[m][n] = __builtin_amdgcn_mfma_f32_16x16x32_f16(ah[m], wl[n], acc[m][n], 0, 0, 0);
        }
      __syncthreads();
    }
  }
  cstat[tid >> 7][tid & 127] = 0.f;
  __syncthreads();
  #pragma unroll
  for (int n = 0; n < 4; ++n) {
    int cl = wc*64 + n*16 + lr;
    int col = n0 + cl;
    float bi = bias[col];
    float s = 0.f, s2 = 0.f;
    #pragma unroll
    for (int m = 0; m < 4; ++m)
      #pragma unroll
      for (int r = 0; r < 4; ++r) {
        int row = t0 + wr*64 + m*16 + kg*4 + r;
        size_t off2 = ((size_t)b*T_ + row)*256 + col;
        float v = fmaxf(acc[m][n][r] + bi, 0.f);
        split2(v, &Ch[off2], &Cl[off2]);
        s += v; s2 += v*v;
      }
    atomicAdd(&cstat[0][cl], s);
    atomicAdd(&cstat[1][cl], s2);
  }
  __syncthreads();
  int f = tid & 127;
  if (tid < 128) atomicAdd(&stats[b*512 + n0 + f],       cstat[0][f]);
  else           atomicAdd(&stats[b*512 + 256 + n0 + f], cstat[1][f]);
}

__global__ __launch_bounds__(256) void finstats_k(float* __restrict__ stats)
{
  int i = blockIdx.x * 256 + threadIdx.x;   // B*256
  int b = i >> 8, f = i & 255;
  float s  = stats[b*512 + f];
  float s2 = stats[b*512 + 256 + f];
  float m  = s * (1.f/T_);
  float v  = s2 * (1.f/T_) - m*m;
  stats[b*512 + f]       = m;
  stats[b*512 + 256 + f] = rsqrtf(fmaxf(v, 0.f) + 1e-5f);
}

// normalized A -> pre-split planes (one elementwise pass)
__global__ __launch_bounds__(256) void norm_split_k(
    const h16* __restrict__ Xh, const h16* __restrict__ Xl,
    const float* __restrict__ stats, h16* __restrict__ Qh, h16* __restrict__ Ql)
{
  size_t base = ((size_t)blockIdx.x*256 + threadIdx.x) * 8;  // over B*T*256
  int f0 = (int)(base & 255);
  int b  = (int)(base >> 21);
  const float* st = stats + b*512;
  half8 xh = *(const half8*)(Xh + base);
  half8 xl = *(const half8*)(Xl + base);
  half8 oh, ol;
  #pragma unroll
  for (int j = 0; j < 8; ++j) {
    float v = join2(xh[j], xl[j]);
    v = (v - st[f0+j]) * st[256 + f0+j];
    h16 hh = (h16)v;
    oh[j] = hh; ol[j] = (h16)(v - (float)hh);
  }
  *(half8*)(Qh + base) = oh;
  *(half8*)(Ql + base) = ol;
}

// ============================================================================
// kv partial: KV[d,e] & Ksum[d] over 512-t chunk, planes input. grid (16,16).
// ============================================================================
__global__ __launch_bounds__(256) void kv_part_p(
    const h16* __restrict__ Kh, const h16* __restrict__ Kl,
    const h16* __restrict__ Vh, const h16* __restrict__ Vl,
    float* __restrict__ pkv)
{
  int bh = blockIdx.y, b = bh >> 2, h = bh & 3;
  int t0 = blockIdx.x * 512;
  __shared__ float Ks[64][68];
  __shared__ float Vs[64][68];
  __shared__ float ksred[64];
  int tid = threadIdx.x;
  int wv = tid >> 6;
  int dq = (tid >> 2) & 15;
  int e4 = tid & 3, e0 = e4 * 16;
  float acc[4][16] = {};
  float ks4[4] = {};
  for (int w = 0; w < 8; ++w) {
    #pragma unroll
    for (int i = 0; i < 2; ++i) {
      int q = tid + i*256;       // 0..511
      int r = q >> 3;
      int c8 = (q & 7) * 8;
      size_t off = ((size_t)b*T_ + t0 + w*64 + r)*256 + h*64 + c8;
      half8 kh = *(const half8*)(Kh + off), kl = *(const half8*)(Kl + off);
      half8 vh = *(const half8*)(Vh + off), vl = *(const half8*)(Vl + off);
      float kf[8], vf[8];
      #pragma unroll
      for (int j = 0; j < 8; ++j) { kf[j] = join2(kh[j], kl[j]); vf[j] = join2(vh[j], vl[j]); }
      *(float4*)&Ks[r][c8]   = *(float4*)&kf[0];
      *(float4*)&Ks[r][c8+4] = *(float4*)&kf[4];
      *(float4*)&Vs[r][c8]   = *(float4*)&vf[0];
      *(float4*)&Vs[r][c8+4] = *(float4*)&vf[4];
    }
    __syncthreads();
    #pragma unroll 4
    for (int tt = wv*16; tt < wv*16 + 16; ++tt) {
      float4 k4 = *(const float4*)&Ks[tt][dq*4];
      if (e4 == 0) {
        ks4[0] += k4.x; ks4[1] += k4.y; ks4[2] += k4.z; ks4[3] += k4.w;
      }
      float va[16];
      *(float4*)&va[0]  = *(const float4*)&Vs[tt][e0+0];
      *(float4*)&va[4]  = *(const float4*)&Vs[tt][e0+4];
      *(float4*)&va[8]  = *(const float4*)&Vs[tt][e0+8];
      *(float4*)&va[12] = *(const float4*)&Vs[tt][e0+12];
      float ka[4] = {k4.x, k4.y, k4.z, k4.w};
      #pragma unroll
      for (int i = 0; i < 4; ++i)
        #pragma unroll
        for (int j = 0; j < 16; ++j)
          acc[i][j] = fmaf(ka[i], va[j], acc[i][j]);
    }
    __syncthreads();
  }
  for (int w = 0; w < 4; ++w) {
    if (wv == w) {
      #pragma unroll
      for (int i = 0; i < 4; ++i) {
        #pragma unroll
        for (int j = 0; j < 16; ++j) {
          if (w == 0) Ks[dq*4+i][e0+j] = acc[i][j];
          else        Ks[dq*4+i][e0+j] += acc[i][j];
        }
        if (e4 == 0) {
          if (w == 0) ksred[dq*4+i] = ks4[i];
          else        ksred[dq*4+i] += ks4[i];
        }
      }
    }
    __syncthreads();
  }
  float* dst = pkv + ((size_t)blockIdx.x*16 + bh)*4160;
  #pragma unroll
  for (int i = 0; i < 16; ++i) {
    int idx = tid + i*256;
    dst[idx] = Ks[idx >> 6][idx & 63];
  }
  if (tid < 64) dst[4096 + tid] = ksred[tid];
}

__global__ __launch_bounds__(256) void kv_final_k(
    const float* __restrict__ pkv, float* __restrict__ kv)
{
  int bh = blockIdx.x;
  for (int idx = threadIdx.x; idx < 4160; idx += 256) {
    float s = 0.f;
    #pragma unroll
    for (int c = 0; c < 16; ++c) s += pkv[((size_t)c*16 + bh)*4160 + idx];
    kv[(size_t)bh*4160 + idx] = s;
  }
}

// ============================================================================
// att apply from planes; O may alias Q (block consumes its tile first).
// ============================================================================
__global__ __launch_bounds__(256) void att_apply_p(
    const h16* __restrict__ Qh, const h16* __restrict__ Ql,
    const float* __restrict__ kv,
    h16* __restrict__ Oh, h16* __restrict__ Ol)
{
  int bh = blockIdx.y, b = bh >> 2, h = bh & 3;
  int t0 = blockIdx.x * 128;
  __shared__ float QsT[64][132];
  __shared__ float KVs[64][68];
  __shared__ float ks[64];
  int tid = threadIdx.x;
  const float* src = kv + (size_t)bh*4160;
  #pragma unroll
  for (int i = 0; i < 16; ++i) {
    int idx = tid + i*256;
    KVs[idx >> 6][idx & 63] = src[idx];
  }
  if (tid < 64) ks[tid] = src[4096 + tid] + 1e-6f;
  #pragma unroll
  for (int i = 0; i < 4; ++i) {
    int q8 = tid + i*256;      // 0..1023
    int t  = q8 >> 3;          // 0..127
    int d8 = (q8 & 7) * 8;
    size_t off = ((size_t)b*T_ + t0 + t)*256 + h*64 + d8;
    half8 qh = *(const half8*)(Qh + off), ql = *(const half8*)(Ql + off);
    #pragma unroll
    for (int j = 0; j < 8; ++j) QsT[d8+j][t] = join2(qh[j], ql[j]);
  }
  __syncthreads();
  int t2 = (tid >> 2) * 2;
  int e0 = (tid & 3) * 16;
  float acc[2][16] = {};
  float den[2] = {};
  for (int dd = 0; dd < 64; ++dd) {
    float2 q = *(const float2*)&QsT[dd][t2];
    float kd = ks[dd];
    den[0] = fmaf(q.x, kd, den[0]);
    den[1] = fmaf(q.y, kd, den[1]);
    float va[16];
    *(float4*)&va[0]  = *(const float4*)&KVs[dd][e0+0];
    *(float4*)&va[4]  = *(const float4*)&KVs[dd][e0+4];
    *(float4*)&va[8]  = *(const float4*)&KVs[dd][e0+8];
    *(float4*)&va[12] = *(const float4*)&KVs[dd][e0+12];
    #pragma unroll
    for (int j = 0; j < 16; ++j) {
      acc[0][j] = fmaf(q.x, va[j], acc[0][j]);
      acc[1][j] = fmaf(q.y, va[j], acc[1][j]);
    }
  }
  #pragma unroll
  for (int ti = 0; ti < 2; ++ti) {
    float z = 1.f / den[ti];
    size_t off = ((size_t)b*T_ + t0 + t2 + ti)*256 + h*64 + e0;
    half8 vh, vl;
    #pragma unroll
    for (int j = 0; j < 8; ++j) {
      float v = acc[ti][j] * z;
      h16 hh = (h16)v; vh[j] = hh; vl[j] = (h16)(v - (float)hh);
    }
    *(half8*)(Oh + off) = vh;
    *(half8*)(Ol + off) = vl;
    #pragma unroll
    for (int j = 0; j < 8; ++j) {
      float v = acc[ti][j+8] * z;
      h16 hh = (h16)v; vh[j] = hh; vl[j] = (h16)(v - (float)hh);
    }
    *(half8*)(Oh + off + 8) = vh;
    *(half8*)(Ol + off + 8) = vl;
  }
}

// ============================================================================
// SFI gram partial (MFMA). Transposed staging with t-offset XOR swizzle
// (((c>>3)&3)<<3): 16-way -> 4-way write conflicts. grid (32,4,B).
// ============================================================================
__global__ __launch_bounds__(256, 2) void gram_part_p(
    const h16* __restrict__ Agh, const h16* __restrict__ Agl,
    const h16* __restrict__ Bgh, const h16* __restrict__ Bgl,
    float* __restrict__ pg)
{
  int b = blockIdx.z;
  int quad = blockIdx.y;
  int slab = blockIdx.x;
  int c0 = (quad >> 1) * 128, d0 = (quad & 1) * 128;
  int t0 = slab * 256;
  __shared__ h16 S[4][128][32];
  int tid = threadIdx.x, l = tid & 63, wid = tid >> 6;
  int wr = wid >> 1, wc = wid & 1, lr = l & 15, kg = l >> 4;
  f32x4 acc[4][4];
  #pragma unroll
  for (int m = 0; m < 4; ++m)
    #pragma unroll
    for (int n = 0; n < 4; ++n) acc[m][n] = (f32x4){0.f,0.f,0.f,0.f};

  for (int k0 = 0; k0 < 256; k0 += 32) {
    #pragma unroll
    for (int i = 0; i < 2; ++i) {
      int q = tid + i*256;       // 0..511
      int tt = q >> 4;           // 0..31
      int c8 = (q & 15) * 8;     // 0..120
      size_t row = ((size_t)b*T_ + t0 + k0 + tt) * 256;
      half8 a8h = *(const half8*)(Agh + row + c0 + c8);
      half8 a8l = *(const half8*)(Agl + row + c0 + c8);
      half8 b8h = *(const half8*)(Bgh + row + d0 + c8);
      half8 b8l = *(const half8*)(Bgl + row + d0 + c8);
      int ts = tt ^ ((q & 3) << 3);       // swizzle key (c8>>3)&3 == q&3
      #pragma unroll
      for (int j = 0; j < 8; ++j) {
        S[0][c8+j][ts] = a8h[j]; S[1][c8+j][ts] = a8l[j];
        S[2][c8+j][ts] = b8h[j]; S[3][c8+j][ts] = b8l[j];
      }
    }
    __syncthreads();
    half8 ah[4], al[4], bh4[4], bl4[4];
    #pragma unroll
    for (int m = 0; m < 4; ++m) {
      int row = wr*64 + m*16 + lr;
      int ko = (kg*8) ^ (((row >> 3) & 3) << 3);
      ah[m] = *(const half8*)&S[0][row][ko];
      al[m] = *(const half8*)&S[1][row][ko];
    }
    #pragma unroll
    for (int n = 0; n < 4; ++n) {
      int row = wc*64 + n*16 + lr;
      int ko = (kg*8) ^ (((row >> 3) & 3) << 3);
      bh4[n] = *(const half8*)&S[2][row][ko];
      bl4[n] = *(const half8*)&S[3][row][ko];
    }
    #pragma unroll
    for (int m = 0; m < 4; ++m)
      #pragma unroll
      for (int n = 0; n < 4; ++n) {
        acc[m][n] = __builtin_amdgcn_mfma_f32_16x16x32_f16(ah[m], bh4[n], acc[m][n], 0, 0, 0);
        acc[m][n] = __builtin_amdgcn_mfma_f32_16x16x32_f16(al[m], bh4[n], acc[m][n], 0, 0, 0);
        acc[m][n] = __builtin_amdgcn_mfma_f32_16x16x32_f16(ah[m], bl4[n], acc[m][n], 0, 0, 0);
      }
    __syncthreads();
  }
  float* dst = pg + ((size_t)(slab*B_ + b)*4 + quad)*16384;
  #pragma unroll
  for (int m = 0; m < 4; ++m)
    #pragma unroll
    for (int n = 0; n < 4; ++n) {
      int cl = wr*64 + m*16 + kg*4;
      int dl = wc*64 + n*16 + lr;
      #pragma unroll
      for (int r = 0; r < 4; ++r)
        dst[(size_t)(cl + r)*128 + dl] = acc[m][n][r];
    }
}

// reduce 32 slabs + softmax(G/T) per row -> G planes. grid (B*256), 64 thr.
__global__ __launch_bounds__(64) void gram_smax_p(
    const float* __restrict__ pg, h16* __restrict__ Gh, h16* __restrict__ Gl)
{
  int row = blockIdx.x;          // b*256 + c
  int b = row >> 8, c = row & 255;
  int l = threadIdx.x;
  int d4 = l * 4;
  int quad = ((c >= 128) ? 2 : 0) | ((d4 >= 128) ? 1 : 0);
  size_t base = ((size_t)b*4 + quad)*16384 + (size_t)(c & 127)*128 + (d4 & 127);
  float s0 = 0.f, s1 = 0.f, s2 = 0.f, s3 = 0.f;
  for (int sl = 0; sl < 32; ++sl) {
    const float* p = pg + (size_t)sl*(B_*4*16384) + base;
    float4 v = *(const float4*)p;
    s0 += v.x; s1 += v.y; s2 += v.z; s3 += v.w;
  }
  float v[4] = {s0*(1.f/T_), s1*(1.f/T_), s2*(1.f/T_), s3*(1.f/T_)};
  float mx = fmaxf(fmaxf(v[0], v[1]), fmaxf(v[2], v[3]));
  #pragma unroll
  for (int off = 32; off > 0; off >>= 1) mx = fmaxf(mx, __shfl_xor(mx, off));
  float s = 0.f;
  #pragma unroll
  for (int j = 0; j < 4; ++j) { v[j] = expf(v[j] - mx); s += v[j]; }
  #pragma unroll
  for (int off = 32; off > 0; off >>= 1) s += __shfl_xor(s, off);
  float inv = 1.f / s;
  size_t doff = (size_t)b*65536 + (size_t)c*256 + d4;
  half4v oh, ol;
  #pragma unroll
  for (int j = 0; j < 4; ++j) {
    float w = v[j] * inv;
    h16 hh = (h16)w; oh[j] = hh; ol[j] = (h16)(w - (float)hh);
  }
  *(half4v*)(Gh + doff) = oh;
  *(half4v*)(Gl + doff) = ol;
}

// ============================================================================
// Final: out[b,o,t] = (fst[b,t,:] . Wn[o,:] + bn[o]) * mask[b,t]
// ============================================================================
__global__ __launch_bounds__(256) void final_p(
    const h16* __restrict__ Ahp, const h16* __restrict__ Alp,
    const float* __restrict__ Wn, const float* __restrict__ bn,
    const float* __restrict__ mask, float* __restrict__ out)
{
  int b = blockIdx.y, t0 = blockIdx.x * 32;
  __shared__ float As[32][257];
  int tid = threadIdx.x;
  #pragma unroll
  for (int i = 0; i < 4; ++i) {
    int q8 = tid + i*256;          // 0..1023
    int rr = q8 >> 5;
    int c8 = (q8 & 31) * 8;
    size_t off = ((size_t)b*T_ + t0 + rr)*256 + c8;
    half8 vh = *(const half8*)(Ahp + off), vl = *(const half8*)(Alp + off);
    float f[8];
    #pragma unroll
    for (int j = 0; j < 8; ++j) f[j] = join2(vh[j], vl[j]);
    *(float4*)&As[rr][c8]   = *(float4*)&f[0];
    *(float4*)&As[rr][c8+4] = *(float4*)&f[4];
  }
  __syncthreads();
  int t  = tid & 31;
  int og = tid >> 5;
  float m = mask[(size_t)b*T_ + t0 + t];
  for (int o = og*6; o < og*6 + 6; ++o) {
    float acc = bn[o];
    const float* wr = Wn + o*256;
    #pragma unroll 8
    for (int c = 0; c < 256; ++c) acc = fmaf(As[t][c], wr[c], acc);
    out[((size_t)b*48 + o)*T_ + t0 + t] = acc * m;
  }
}

// ============================================================================
extern "C" void kernel_launch(void* const* d_in, const int* in_sizes, int n_in,
                              void* d_out, int out_size, void* d_ws, size_t ws_size,
                              hipStream_t stream) {
  const float* x         = (const float*)d_in[0];
  const float* mask      = (const float*)d_in[1];
  const float* conv_in_w = (const float*)d_in[2];
  const float* conv_in_b = (const float*)d_in[3];
  const float* conv_t_w  = (const float*)d_in[4];
  const float* conv_t_b  = (const float*)d_in[5];
  const float* sfi_cs_w  = (const float*)d_in[6];
  const float* sfi_cs_b  = (const float*)d_in[7];
  const float* sfi_ff1_w = (const float*)d_in[8];
  const float* sfi_ff1_b = (const float*)d_in[9];
  const float* sfi_ff2_w = (const float*)d_in[10];
  const float* sfi_ff2_b = (const float*)d_in[11];
  const float* ff_w      = (const float*)d_in[12];
  const float* ff_b      = (const float*)d_in[13];
  const float* qw = (const float*)d_in[14]; const float* qb = (const float*)d_in[15];
  const float* kw = (const float*)d_in[16]; const float* kb = (const float*)d_in[17];
  const float* vw = (const float*)d_in[18]; const float* vb = (const float*)d_in[19];
  const float* ow = (const float*)d_in[20]; const float* ob = (const float*)d_in[21];
  const float* co_w = (const float*)d_in[22]; const float* co_b = (const float*)d_in[23];
  const float* out_w = (const float*)d_in[24]; const float* out_b = (const float*)d_in[25];

  float* ws = (float*)d_ws;
  const size_t BT = (size_t)B_ * T_;
  const size_t NB = BT * 256;               // elements per big buffer
  // ---- regions (f32 units), ~178 MB ----
  float* smallR = ws;                        // BT*64  (fs planes / pkv / wlay)
  float* bigR   = smallR + BT*64;            // 5 * NB
  float* GR     = bigR + 5*NB;               // B*65536
  float* statsR = GR + (size_t)B_*65536;     // B*512
  float* kvR    = statsR + (size_t)B_*512;   // 16*4160
  float* wsfiR  = kvR + 16*4160;             // 147456
  float* zbufR  = wsfiR + 147456;            // 16 floats (zero page)

  h16* small_h = (h16*)smallR; h16* small_l = small_h + BT*64;
  h16 *bigH[5], *bigL[5];
  for (int i = 0; i < 5; ++i) { bigH[i] = (h16*)(bigR + (size_t)i*NB); bigL[i] = bigH[i] + NB; }
  h16* G_h = (h16*)GR; h16* G_l = G_h + (size_t)B_*65536;
  float* stats = statsR;
  float* kvbuf = kvR;
  h16* wsfi_h = (h16*)wsfiR; h16* wsfi_l = wsfi_h + 147456;
  // aliased into small (dead between SFI fs usage): pkv + per-layer weights
  float* pkv   = smallR;                              // 16*16*4160 = 1064960 f32
  h16* wlay_h  = (h16*)(smallR + 1064960);            // 8*65536 elements
  h16* wlay_l  = wlay_h + 8*65536;

  dim3 gh(2, T_/128, B_);
  dim3 b256(256);

  hipMemsetAsync(zbufR, 0, 64, stream);
  // xi5 -> small planes; conv_t split -> wsfi[0..16384)
  init_fs_k<<<dim3((unsigned)(BT*64/256)), b256, 0, stream>>>(x, conv_in_w, conv_in_b, small_h, small_l, 4);
  wsplit_k<<<dim3(64), b256, 0, stream>>>(conv_t_w, wsfi_h, wsfi_l, 16384);
  gemm_p<0><<<gh, b256, 0, stream>>>(small_h, small_l, wsfi_h, wsfi_l, conv_t_b,
                                     nullptr, nullptr, bigH[0], bigL[0], 64, 0);

  int fi = 0, fo = 1;   // fst = big[fi], fstN = big[fo]
  int count = 0;
  for (int i = 0; i < 10; ++i) {
    if (i == 1 || i == 3 || i == 5 || i == 7) {
      // ---- SFI ----
      sprep_k<<<dim3(576), b256, 0, stream>>>(sfi_ff1_w + (size_t)count*65536,
                                              sfi_ff2_w + (size_t)count*65536,
                                              sfi_cs_w + (size_t)count*16384,
                                              wsfi_h, wsfi_l);
      init_fs_k<<<dim3((unsigned)(BT*64/256)), b256, 0, stream>>>(x, conv_in_w, conv_in_b, small_h, small_l, count);
      gemm_p<0><<<gh, b256, 0, stream>>>(small_h, small_l, wsfi_h + 131072, wsfi_l + 131072,
                                         sfi_cs_b + count*256, nullptr, nullptr,
                                         bigH[2], bigL[2], 64, 0);
      float* pgram = bigR + (size_t)fo*NB;  // dead f32 region (exactly NB floats)
      gram_part_p<<<dim3(32, 4, B_), b256, 0, stream>>>(bigH[2], bigL[2], bigH[fi], bigL[fi], pgram);
      gram_smax_p<<<dim3(B_*256), dim3(64), 0, stream>>>(pgram, G_h, G_l);
      gemm_p<0><<<gh, b256, 0, stream>>>(bigH[fi], bigL[fi], G_h, G_l, nullptr,
                                         bigH[fi], bigL[fi], bigH[3], bigL[3], 256, 65536);
      gemm_p<3><<<gh, b256, 0, stream>>>(bigH[3], bigL[3], wsfi_h, wsfi_l,
                                         sfi_ff1_b + count*256, nullptr, nullptr,
                                         bigH[4], bigL[4], 256, 0);
      gemm_p<0><<<gh, b256, 0, stream>>>(bigH[4], bigL[4], wsfi_h + 65536, wsfi_l + 65536,
                                         sfi_ff2_b + count*256, bigH[fi], bigL[fi],
                                         bigH[fo], bigL[fo], 256, 0);
      int t = fi; fi = fo; fo = t;
      ++count;
    }
    // ---- attention module ----
    int dil = 1 << i;
    wprep_k<<<dim3(2048), b256, 0, stream>>>(ff_w + (size_t)i*196608,
                                             qw + (size_t)i*65536, kw + (size_t)i*65536,
                                             vw + (size_t)i*65536, ow + (size_t)i*65536,
                                             co_w + (size_t)i*65536, wlay_h, wlay_l);
    hipMemsetAsync(stats, 0, (size_t)B_*512*sizeof(float), stream);
    conv_p<<<gh, b256, 0, stream>>>(bigH[fi], bigL[fi], wlay_h, wlay_l, ff_b + i*256,
                                    bigH[fo], bigL[fo], stats, zbufR, dil);
    finstats_k<<<dim3(B_), b256, 0, stream>>>(stats);
    norm_split_k<<<dim3((unsigned)(NB/2048)), b256, 0, stream>>>(bigH[fo], bigL[fo], stats,
                                                                 bigH[2], bigL[2]);
    // K (sigmoid) -> big3, V -> big4
    gemm_p<2><<<gh, b256, 0, stream>>>(bigH[2], bigL[2], wlay_h + 262144, wlay_l + 262144,
                                       kb + i*256, nullptr, nullptr, bigH[3], bigL[3], 256, 0);
    gemm_p<0><<<gh, b256, 0, stream>>>(bigH[2], bigL[2], wlay_h + 327680, wlay_l + 327680,
                                       vb + i*256, nullptr, nullptr, bigH[4], bigL[4], 256, 0);
    kv_part_p<<<dim3(16, 16), b256, 0, stream>>>(bigH[3], bigL[3], bigH[4], bigL[4], pkv);
    kv_final_k<<<dim3(16), b256, 0, stream>>>(pkv, kvbuf);
    // Q (sigmoid) -> big3 (K dead after kv_part)
    gemm_p<2><<<gh, b256, 0, stream>>>(bigH[2], bigL[2], wlay_h + 196608, wlay_l + 196608,
                                       qb + i*256, nullptr, nullptr, bigH[3], bigL[3], 256, 0);
    att_apply_p<<<dim3(T_/128, 16), b256, 0, stream>>>(bigH[3], bigL[3], kvbuf, bigH[3], bigL[3]);
    // o-proj + conv resid -> big4 ; co-proj + fst resid -> fstN
    gemm_p<0><<<gh, b256, 0, stream>>>(bigH[3], bigL[3], wlay_h + 393216, wlay_l + 393216,
                                       ob + i*256, bigH[fo], bigL[fo], bigH[4], bigL[4], 256, 0);
    gemm_p<0><<<gh, b256, 0, stream>>>(bigH[4], bigL[4], wlay_h + 458752, wlay_l + 458752,
                                       co_b + i*256, bigH[fi], bigL[fi], bigH[fo], bigL[fo], 256, 0);
    int t = fi; fi = fo; fo = t;
  }
  final_p<<<dim3(T_/32, B_), b256, 0, stream>>>(bigH[fi], bigL[fi], out_w, out_b, mask, (float*)d_out);
}